// Round 15
// baseline (457.048 us; speedup 1.0000x reference)
//
#include <hip/hip_runtime.h>

#define DEVI __device__ __forceinline__

typedef __bf16 bf16x8 __attribute__((ext_vector_type(8)));
typedef float f32x4 __attribute__((ext_vector_type(4)));

DEVI ushort f2b(float f) {            // f32 -> bf16 RNE
  uint b = __float_as_uint(f);
  uint r = (b + 0x7FFFu + ((b >> 16) & 1u)) >> 16;
  return (ushort)r;
}
DEVI float b2f(ushort u) { return __uint_as_float(((uint)u) << 16); }

// ======================= weight prep: all convs -> bf16 Wb[tap][co][ci] =======================
struct PrepArgs {
  int nw;
  int tot[20];
  const float* src[20];
  ushort* dst[20];
  int ci[20], co[20], sco[20], sci[20], sk[20];
};

__global__ __launch_bounds__(256)
void prep_all(PrepArgs a, int total) {
  int i = blockIdx.x * 256 + threadIdx.x;
  if (i >= total) return;
  int w = 0;
  while (i >= a.tot[w]) { i -= a.tot[w]; ++w; }
  const int li = i;
  const int CI = a.ci[w];
  int ciX = i % CI;
  int rest = i / CI;
  int coX = rest % a.co[w];
  int k = rest / a.co[w];
  a.dst[w][li] = f2b(a.src[w][coX * a.sco[w] + ciX * a.sci[w] + k * a.sk[w]]);
}

// ======================= fused enc1+enc2 (v2) =======================
__global__ __launch_bounds__(256)
void enc12_mfma(const float* __restrict__ x, const float* __restrict__ w1,
                const float* __restrict__ b1, const ushort* __restrict__ wb,
                const float* __restrict__ b2, ushort* __restrict__ out) {
  constexpr int CI = 64, CO = 128, K = 4, TT = 64;
  constexpr int SPAN = 2 * (TT - 1) + K;       // 130 e1 rows
  __shared__ __align__(16) ushort xs[SPAN * CI];
  __shared__ float xl[264];
  __shared__ float w1s[256];
  __shared__ float b1s[64];

  const int n = blockIdx.x >> 4;
  const int t0 = (blockIdx.x & 15) * TT;
  const int tid = threadIdx.x;
  const int wid = tid >> 6, lane = tid & 63;
  const int l15 = lane & 15, l4 = lane >> 4;

  const int t_in0 = 2 * t0 - 1;
  const int xw0 = 2 * t_in0 - 1;
  const float* xb = x + ((size_t)n << 12);

  for (int j = tid; j < 262; j += 256)
    xl[j] = xb[(xw0 + j + 8192) & 4095];
  if (tid < 256) w1s[tid] = w1[tid];
  if (tid < 64) b1s[tid] = b1[tid];
  __syncthreads();

  const int g = tid & 7;
  float4 wv[8];
  float bs[8];
  #pragma unroll
  for (int e = 0; e < 8; ++e) {
    wv[e] = *reinterpret_cast<const float4*>(&w1s[(g * 8 + e) * 4]);
    bs[e] = b1s[g * 8 + e];
  }
  #pragma unroll
  for (int it = 0; it < 5; ++it) {
    int t = it * 32 + (tid >> 3);
    if (t < SPAN) {
      float x0 = xl[2 * t], x1 = xl[2 * t + 1], x2 = xl[2 * t + 2], x3 = xl[2 * t + 3];
      uint pack[4];
      #pragma unroll
      for (int h = 0; h < 4; ++h) {
        float s0 = fmaf(wv[2 * h].x, x0, fmaf(wv[2 * h].y, x1,
                   fmaf(wv[2 * h].z, x2, fmaf(wv[2 * h].w, x3, bs[2 * h]))));
        float s1 = fmaf(wv[2 * h + 1].x, x0, fmaf(wv[2 * h + 1].y, x1,
                   fmaf(wv[2 * h + 1].z, x2, fmaf(wv[2 * h + 1].w, x3, bs[2 * h + 1]))));
        pack[h] = (uint)f2b(fmaxf(s0, 0.0f)) | ((uint)f2b(fmaxf(s1, 0.0f)) << 16);
      }
      *reinterpret_cast<uint4*>(&xs[t * CI + ((g ^ ((t >> 1) & 7)) * 8)]) =
          uint4{pack[0], pack[1], pack[2], pack[3]};
    }
  }
  __syncthreads();

  const int co_base = wid * 32;
  f32x4 acc[4][2] = {};
  for (int cc = 0; cc < 2; ++cc) {
    bf16x8 bk[K][2];
    #pragma unroll
    for (int k = 0; k < K; ++k)
      #pragma unroll
      for (int c = 0; c < 2; ++c)
        bk[k][c] = __builtin_bit_cast(bf16x8, *reinterpret_cast<const uint4*>(
            wb + (size_t)((k * CO + co_base + c * 16 + l15)) * CI + cc * 32 + l4 * 8));
    #pragma unroll
    for (int k = 0; k < K; ++k) {
      #pragma unroll
      for (int tt2 = 0; tt2 < 4; ++tt2) {
        int trow = 2 * (tt2 * 16 + l15) + k;
        int gg = cc * 4 + l4;
        bf16x8 afr = __builtin_bit_cast(bf16x8, *reinterpret_cast<const uint4*>(
            &xs[trow * CI + ((gg ^ ((trow >> 1) & 7)) * 8)]));
        #pragma unroll
        for (int c = 0; c < 2; ++c)
          acc[tt2][c] = __builtin_amdgcn_mfma_f32_16x16x32_bf16(afr, bk[k][c], acc[tt2][c], 0, 0, 0);
      }
    }
  }
  float bv[2];
  #pragma unroll
  for (int c = 0; c < 2; ++c) bv[c] = b2[co_base + c * 16 + l15];
  ushort* outb = out + (size_t)n * 1024 * CO;
  #pragma unroll
  for (int tt2 = 0; tt2 < 4; ++tt2)
    #pragma unroll
    for (int c = 0; c < 2; ++c)
      #pragma unroll
      for (int r = 0; r < 4; ++r) {
        int t = t0 + tt2 * 16 + 4 * l4 + r;
        int co = co_base + c * 16 + l15;
        outb[(size_t)t * CO + co] = f2b(fmaxf(acc[tt2][c][r] + bv[c], 0.0f));
      }
}

// ======================= generalized MFMA forward conv (optionally ci-chunked) ===============
template<int CI, int CO, int K, int S, bool CIRC, bool GATHER, int NT, int WAVES_CO,
         int NCHUNK = 1>
__global__ __launch_bounds__(256)
void conv_mfma(const ushort* __restrict__ in, const ushort* __restrict__ wb,
               const float* __restrict__ bias, const ushort* __restrict__ resid,
               ushort* __restrict__ out, const int* __restrict__ gidx,
               int Tin, int in_relu, int out_relu) {
  constexpr int PAD = (K > 1) ? 1 : 0;
  constexpr int TT = NT * 16;
  constexpr int SPAN = S * (TT - 1) + K;
  constexpr int CICH = CI / NCHUNK;
  constexpr int CIGc = CICH / 8;
  constexpr int COT = CO / 16;
  constexpr int WCOT = COT / WAVES_CO;
  constexpr int WAVES_T = 4 / WAVES_CO;
  constexpr int WTT = NT / WAVES_T;
  constexpr int KSH = (S == 2) ? 1 : 0;
  static_assert(CICH % 32 == 0 && COT % WAVES_CO == 0 && NT % WAVES_T == 0, "");

  __shared__ __align__(16) ushort xs[SPAN * CICH];

  const int Tout = Tin / S;
  const int tilesPerB = Tout / TT;
  const int n = blockIdx.x / tilesPerB;
  const int t0 = (blockIdx.x % tilesPerB) * TT;
  const int tid = threadIdx.x;
  const int wid = tid >> 6, lane = tid & 63;
  const int l15 = lane & 15, l4 = lane >> 4;

  const int t_in0 = S * t0 - PAD;
  const ushort* inb = GATHER ? in : in + (size_t)n * Tin * CI;

  const int wco = wid % WAVES_CO;
  const int wt = wid / WAVES_CO;
  const int co_base = wco * WCOT * 16;
  const int t_base = wt * WTT * 16;

  f32x4 acc[WTT][WCOT] = {};

  for (int h = 0; h < NCHUNK; ++h) {
    if (h) __syncthreads();
    for (int i = tid; i < SPAN * CIGc; i += 256) {
      int t = i / CIGc, g = i - (i / CIGc) * CIGc;
      int tg = t_in0 + t;
      uint4 v;
      if (CIRC) {
        tg = (tg < 0) ? tg + Tin : (tg >= Tin ? tg - Tin : tg);
        v = *reinterpret_cast<const uint4*>(inb + (size_t)tg * CI + h * CICH + g * 8);
      } else if (GATHER) {
        if ((unsigned)tg < (unsigned)Tin) {
          int id = gidx[n * Tin + tg];
          v = *reinterpret_cast<const uint4*>(inb + (size_t)id * CI + h * CICH + g * 8);
        } else
          v = uint4{0, 0, 0, 0};
      } else {
        if ((unsigned)tg < (unsigned)Tin)
          v = *reinterpret_cast<const uint4*>(inb + (size_t)tg * CI + h * CICH + g * 8);
        else
          v = uint4{0, 0, 0, 0};
      }
      if (in_relu) {
        ushort* pv = reinterpret_cast<ushort*>(&v);
        #pragma unroll
        for (int e = 0; e < 8; ++e) pv[e] = (pv[e] & 0x8000) ? 0 : pv[e];
      }
      *reinterpret_cast<uint4*>(&xs[t * CICH + ((g ^ ((t >> KSH) & (CIGc - 1))) * 8)]) = v;
    }
    __syncthreads();

    for (int cc = 0; cc < CICH / 32; ++cc) {
      const int ccg = h * (CICH / 32) + cc;
      bf16x8 bk[K][WCOT];
      #pragma unroll
      for (int k = 0; k < K; ++k)
        #pragma unroll
        for (int c = 0; c < WCOT; ++c)
          bk[k][c] = __builtin_bit_cast(bf16x8, *reinterpret_cast<const uint4*>(
              wb + (size_t)((k * CO + co_base + c * 16 + l15)) * CI + ccg * 32 + l4 * 8));
      #pragma unroll
      for (int k = 0; k < K; ++k) {
        #pragma unroll
        for (int tt2 = 0; tt2 < WTT; ++tt2) {
          int trow = S * (t_base + tt2 * 16 + l15) + k;
          int g = cc * 4 + l4;
          bf16x8 afr = __builtin_bit_cast(bf16x8, *reinterpret_cast<const uint4*>(
              &xs[trow * CICH + ((g ^ ((trow >> KSH) & (CIGc - 1))) * 8)]));
          #pragma unroll
          for (int c = 0; c < WCOT; ++c)
            acc[tt2][c] = __builtin_amdgcn_mfma_f32_16x16x32_bf16(afr, bk[k][c], acc[tt2][c], 0, 0, 0);
        }
      }
    }
  }

  float bv[WCOT];
  #pragma unroll
  for (int c = 0; c < WCOT; ++c)
    bv[c] = bias ? bias[co_base + c * 16 + l15] : 0.0f;
  ushort* outb = out + (size_t)n * Tout * CO;
  const ushort* resb = resid ? resid + (size_t)n * Tout * CO : nullptr;
  #pragma unroll
  for (int tt2 = 0; tt2 < WTT; ++tt2)
    #pragma unroll
    for (int c = 0; c < WCOT; ++c)
      #pragma unroll
      for (int r = 0; r < 4; ++r) {
        int t = t0 + t_base + tt2 * 16 + 4 * l4 + r;
        int co = co_base + c * 16 + l15;
        float v = acc[tt2][c][r] + bv[c];
        if (resb) v += b2f(resb[(size_t)t * CO + co]);
        if (out_relu) v = fmaxf(v, 0.0f);
        outb[(size_t)t * CO + co] = f2b(v);
      }
}

// ======================= fused residual layer (hs aliased into xs) =======================
__global__ __launch_bounds__(256)
void res_mfma(const ushort* __restrict__ in, const ushort* __restrict__ wb1,
              const ushort* __restrict__ wb2, ushort* __restrict__ out) {
  constexpr int CI = 128, CIG = 16;
  constexpr int TT = 64, SPAN = 66, Tin = 256;
  __shared__ __align__(16) ushort xs[SPAN * CI];
  ushort* hs = xs;
  const int n = blockIdx.x >> 2;
  const int t0 = (blockIdx.x & 3) * TT;
  const int tid = threadIdx.x;
  const int wid = tid >> 6, lane = tid & 63;
  const int l15 = lane & 15, l4 = lane >> 4;
  const int t_in0 = t0 - 1;
  const ushort* inb = in + (size_t)n * Tin * CI;

  for (int i = tid; i < SPAN * CIG; i += 256) {
    int t = i >> 4, g = i & 15;
    int tg = t_in0 + t;
    tg = (tg < 0) ? tg + Tin : (tg >= Tin ? tg - Tin : tg);
    uint4 v = *reinterpret_cast<const uint4*>(inb + (size_t)tg * CI + g * 8);
    ushort* pv = reinterpret_cast<ushort*>(&v);
    #pragma unroll
    for (int e = 0; e < 8; ++e) pv[e] = (pv[e] & 0x8000) ? 0 : pv[e];
    *reinterpret_cast<uint4*>(&xs[t * CI + ((g ^ (t & 15)) * 8)]) = v;
  }
  __syncthreads();

  f32x4 acc1[2] = {};
  for (int cc = 0; cc < 4; ++cc)
    #pragma unroll
    for (int k = 0; k < 3; ++k) {
      bf16x8 bfr[2];
      #pragma unroll
      for (int c = 0; c < 2; ++c)
        bfr[c] = __builtin_bit_cast(bf16x8, *reinterpret_cast<const uint4*>(
            wb1 + (size_t)((k * 32 + c * 16 + l15)) * CI + cc * 32 + l4 * 8));
      int trow = wid * 16 + l15 + k;
      int g = cc * 4 + l4;
      bf16x8 afr = __builtin_bit_cast(bf16x8, *reinterpret_cast<const uint4*>(
          &xs[trow * CI + ((g ^ (trow & 15)) * 8)]));
      acc1[0] = __builtin_amdgcn_mfma_f32_16x16x32_bf16(afr, bfr[0], acc1[0], 0, 0, 0);
      acc1[1] = __builtin_amdgcn_mfma_f32_16x16x32_bf16(afr, bfr[1], acc1[1], 0, 0, 0);
    }
  __syncthreads();
  #pragma unroll
  for (int c = 0; c < 2; ++c)
    #pragma unroll
    for (int r = 0; r < 4; ++r) {
      float v = acc1[c][r];
      hs[(wid * 16 + l4 * 4 + r) * 40 + c * 16 + l15] = (v > 0.0f) ? f2b(v) : (ushort)0;
    }
  __syncthreads();

  {
    bf16x8 afr = *reinterpret_cast<const bf16x8*>(&hs[(wid * 16 + l15) * 40 + l4 * 8]);
    f32x4 acc[8];
    #pragma unroll
    for (int c = 0; c < 8; ++c) {
      bf16x8 bfr = __builtin_bit_cast(bf16x8, *reinterpret_cast<const uint4*>(
          wb2 + (size_t)(c * 16 + l15) * 32 + l4 * 8));
      f32x4 z = {};
      acc[c] = __builtin_amdgcn_mfma_f32_16x16x32_bf16(afr, bfr, z, 0, 0, 0);
    }
    ushort* outb = out + (size_t)n * Tin * CI;
    #pragma unroll
    for (int c = 0; c < 8; ++c)
      #pragma unroll
      for (int r = 0; r < 4; ++r) {
        int t = t0 + wid * 16 + l4 * 4 + r;
        int co = c * 16 + l15;
        float v = acc[c][r] + b2f(inb[(size_t)t * CI + co]);
        outb[(size_t)t * CI + co] = f2b(v);
      }
  }
}

// ======================= MFMA transposed conv k=4 s=2 p=1 (CI=128) =======================
template<int CO>
__global__ __launch_bounds__(256, 2)
void convt_mfma(const ushort* __restrict__ in, const ushort* __restrict__ wb,
                const float* __restrict__ bias, ushort* __restrict__ out,
                int Tin, int in_relu, int out_relu) {
  constexpr int CI = 128, CIG = 16;
  constexpr int NT = 4, TT = 64;
  constexpr int SPAN = TT + 2;
  constexpr int COT = CO / 16;
  constexpr int WCOT = (COT + 3) / 4;
  constexpr int WAVES_CO = COT / WCOT;
  constexpr int WTT = NT;

  __shared__ __align__(16) ushort xs[SPAN * CI];

  const int Tout = 2 * Tin;
  const int tilesPerB = Tin / TT;
  const int n = blockIdx.x / tilesPerB;
  const int tp0 = (blockIdx.x % tilesPerB) * TT;
  const int tid = threadIdx.x;
  const int wid = tid >> 6, lane = tid & 63;
  const int l15 = lane & 15, l4 = lane >> 4;

  const int t_in0 = tp0 - 1;
  const ushort* inb = in + (size_t)n * Tin * CI;
  for (int i = tid; i < SPAN * CIG; i += 256) {
    int t = i >> 4, g = i & 15;
    int tg = t_in0 + t;
    uint4 v;
    if ((unsigned)tg < (unsigned)Tin)
      v = *reinterpret_cast<const uint4*>(inb + (size_t)tg * CI + g * 8);
    else
      v = uint4{0, 0, 0, 0};
    if (in_relu) {
      ushort* pv = reinterpret_cast<ushort*>(&v);
      #pragma unroll
      for (int e = 0; e < 8; ++e) pv[e] = (pv[e] & 0x8000) ? 0 : pv[e];
    }
    *reinterpret_cast<uint4*>(&xs[t * CI + ((g ^ (t & 15)) * 8)]) = v;
  }
  __syncthreads();

  const int wco = wid % WAVES_CO;
  const int co_base = wco * WCOT * 16;

  f32x4 accE[WTT][WCOT] = {};
  f32x4 accO[WTT][WCOT] = {};

  for (int cc = 0; cc < 4; ++cc) {
    bf16x8 bk[4][WCOT];
    #pragma unroll
    for (int k = 0; k < 4; ++k)
      #pragma unroll
      for (int c = 0; c < WCOT; ++c)
        bk[k][c] = __builtin_bit_cast(bf16x8, *reinterpret_cast<const uint4*>(
            wb + (size_t)((k * CO + co_base + c * 16 + l15)) * CI + cc * 32 + l4 * 8));
    #pragma unroll
    for (int tt2 = 0; tt2 < WTT; ++tt2) {
      int lt = tt2 * 16 + l15 + 1;
      int g = cc * 4 + l4;
      bf16x8 a0 = __builtin_bit_cast(bf16x8, *reinterpret_cast<const uint4*>(
          &xs[lt * CI + ((g ^ (lt & 15)) * 8)]));
      bf16x8 am = __builtin_bit_cast(bf16x8, *reinterpret_cast<const uint4*>(
          &xs[(lt - 1) * CI + ((g ^ ((lt - 1) & 15)) * 8)]));
      bf16x8 ap = __builtin_bit_cast(bf16x8, *reinterpret_cast<const uint4*>(
          &xs[(lt + 1) * CI + ((g ^ ((lt + 1) & 15)) * 8)]));
      #pragma unroll
      for (int c = 0; c < WCOT; ++c) {
        accE[tt2][c] = __builtin_amdgcn_mfma_f32_16x16x32_bf16(a0, bk[1][c], accE[tt2][c], 0, 0, 0);
        accE[tt2][c] = __builtin_amdgcn_mfma_f32_16x16x32_bf16(am, bk[3][c], accE[tt2][c], 0, 0, 0);
        accO[tt2][c] = __builtin_amdgcn_mfma_f32_16x16x32_bf16(ap, bk[0][c], accO[tt2][c], 0, 0, 0);
        accO[tt2][c] = __builtin_amdgcn_mfma_f32_16x16x32_bf16(a0, bk[2][c], accO[tt2][c], 0, 0, 0);
      }
    }
  }

  float bv[WCOT];
  #pragma unroll
  for (int c = 0; c < WCOT; ++c) bv[c] = bias[co_base + c * 16 + l15];
  ushort* outb = out + (size_t)n * Tout * CO;
  #pragma unroll
  for (int tt2 = 0; tt2 < WTT; ++tt2)
    #pragma unroll
    for (int c = 0; c < WCOT; ++c)
      #pragma unroll
      for (int r = 0; r < 4; ++r) {
        int tp = tp0 + tt2 * 16 + 4 * l4 + r;
        int co = co_base + c * 16 + l15;
        float vE = accE[tt2][c][r] + bv[c];
        float vO = accO[tt2][c][r] + bv[c];
        if (out_relu) { vE = fmaxf(vE, 0.0f); vO = fmaxf(vO, 0.0f); }
        outb[(size_t)(2 * tp) * CO + co] = f2b(vE);
        outb[(size_t)(2 * tp + 1) * CO + co] = f2b(vO);
      }
}

// ======================= fused ct2+ct3 (TT=64) =======================
// ys transposed [j][66] aliased onto xs; conflict-free; 18.2 KB LDS.
// launch_bounds(256,8) forces VGPR<=64 (was 68) -> 8 waves/SIMD cap.
__global__ __launch_bounds__(256, 8)
void ct23_mfma(const ushort* __restrict__ in, const ushort* __restrict__ wb,
               const float* __restrict__ bias, const float* __restrict__ w3,
               const float* __restrict__ b3, float* __restrict__ out) {
  constexpr int CI = 128, CO = 64, CIG = 16;
  constexpr int TT = 64, SPAN = 66, Tin = 1024;
  __shared__ __align__(16) ushort buf[8580];
  __shared__ float2 w3p[2][64];
  ushort* xs = buf;
  ushort* ys = buf;

  const int n = blockIdx.x >> 4;
  const int tp0 = (blockIdx.x & 15) * TT;
  const int tid = threadIdx.x;
  const int wid = tid >> 6, lane = tid & 63;
  const int l15 = lane & 15, l4 = lane >> 4;
  const int t_in0 = tp0 - 1;
  const ushort* inb = in + (size_t)n * Tin * CI;

  if (tid < 128) {
    int parity = tid >> 6, ci = tid & 63;
    w3p[parity][ci] = parity
        ? float2{w3[ci * 4 + 0], w3[ci * 4 + 2]}
        : float2{w3[ci * 4 + 1], w3[ci * 4 + 3]};
  }
  for (int i = tid; i < SPAN * CIG; i += 256) {
    int t = i >> 4, g = i & 15;
    int tg = t_in0 + t;
    uint4 v;
    if ((unsigned)tg < (unsigned)Tin)
      v = *reinterpret_cast<const uint4*>(inb + (size_t)tg * CI + g * 8);
    else
      v = uint4{0, 0, 0, 0};
    *reinterpret_cast<uint4*>(&xs[t * CI + ((g ^ (t & 15)) * 8)]) = v;
  }
  __syncthreads();

  const int co = wid * 16 + l15;
  f32x4 accE[4] = {}, accO[4] = {};
  f32x4 hO = {}, hE = {};

  for (int cc = 0; cc < 4; ++cc) {
    bf16x8 bk[4];
    #pragma unroll
    for (int k = 0; k < 4; ++k)
      bk[k] = __builtin_bit_cast(bf16x8, *reinterpret_cast<const uint4*>(
          wb + (size_t)((k * CO + co)) * CI + cc * 32 + l4 * 8));
    const int g = cc * 4 + l4;
    auto rd = [&](int lt) -> bf16x8 {
      return __builtin_bit_cast(bf16x8, *reinterpret_cast<const uint4*>(
          &xs[lt * CI + ((g ^ (lt & 15)) * 8)]));
    };
    #pragma unroll
    for (int tt2 = 0; tt2 < 4; ++tt2) {
      int lt = tt2 * 16 + l15 + 1;
      bf16x8 a0 = rd(lt), am = rd(lt - 1), ap = rd(lt + 1);
      accE[tt2] = __builtin_amdgcn_mfma_f32_16x16x32_bf16(a0, bk[1], accE[tt2], 0, 0, 0);
      accE[tt2] = __builtin_amdgcn_mfma_f32_16x16x32_bf16(am, bk[3], accE[tt2], 0, 0, 0);
      accO[tt2] = __builtin_amdgcn_mfma_f32_16x16x32_bf16(ap, bk[0], accO[tt2], 0, 0, 0);
      accO[tt2] = __builtin_amdgcn_mfma_f32_16x16x32_bf16(a0, bk[2], accO[tt2], 0, 0, 0);
    }
    bf16x8 h0 = rd(0), h1 = rd(1), h64 = rd(64), h65 = rd(65);
    hO = __builtin_amdgcn_mfma_f32_16x16x32_bf16(h1, bk[0], hO, 0, 0, 0);
    hO = __builtin_amdgcn_mfma_f32_16x16x32_bf16(h0, bk[2], hO, 0, 0, 0);
    hE = __builtin_amdgcn_mfma_f32_16x16x32_bf16(h65, bk[1], hE, 0, 0, 0);
    hE = __builtin_amdgcn_mfma_f32_16x16x32_bf16(h64, bk[3], hE, 0, 0, 0);
  }
  __syncthreads();

  const float bv = bias[co];
  #pragma unroll
  for (int tt2 = 0; tt2 < 4; ++tt2)
    #pragma unroll
    for (int r = 0; r < 4; ++r) {
      int m = tt2 * 16 + 4 * l4 + r;
      ys[(2 * m + 1) * 66 + co] = f2b(fmaxf(accE[tt2][r] + bv, 0.0f));
      ys[(2 * m + 2) * 66 + co] = f2b(fmaxf(accO[tt2][r] + bv, 0.0f));
    }
  if (l4 == 0) {
    ys[co]            = (tp0 == 0) ? (ushort)0 : f2b(fmaxf(hO[0] + bv, 0.0f));
    ys[129 * 66 + co] = (tp0 + TT == Tin) ? (ushort)0 : f2b(fmaxf(hE[0] + bv, 0.0f));
  }
  __syncthreads();

  const int o = 4 * tp0 + tid;
  const int odd = tid & 1;
  const int ha = (tid + odd) >> 1;
  const ushort* ra = &ys[(ha + 1) * 66];
  const ushort* rb = &ys[ha * 66];
  const float2* wp = w3p[odd];
  float s = b3[0];
  #pragma unroll
  for (int c = 0; c < 32; ++c) {
    uint va = *reinterpret_cast<const uint*>(ra + 2 * c);
    uint vb = *reinterpret_cast<const uint*>(rb + 2 * c);
    float2 w0 = wp[2 * c], w1 = wp[2 * c + 1];
    s = fmaf(w0.x, __uint_as_float(va << 16), s);
    s = fmaf(w1.x, __uint_as_float(va & 0xFFFF0000u), s);
    s = fmaf(w0.y, __uint_as_float(vb << 16), s);
    s = fmaf(w1.y, __uint_as_float(vb & 0xFFFF0000u), s);
  }
  out[(size_t)n * 4096 + o] = s;
}

// ======================= VQ =======================
__global__ __launch_bounds__(256)
void vq_mfma(const ushort* __restrict__ zt, const ushort* __restrict__ embb,
             int* __restrict__ idx, int* __restrict__ hist,
             float* __restrict__ loss_accum) {
  __shared__ __align__(16) ushort es[512 * 64];
  __shared__ float eel[512];
  __shared__ int lhist[512];
  const int tid = threadIdx.x;
  const int wid = tid >> 6, lane = tid & 63;
  const int l15 = lane & 15, l4 = lane >> 4;

  for (int i = tid; i < 512 * 8; i += 256) {
    int c = i >> 3, g = i & 7;
    uint4 v = reinterpret_cast<const uint4*>(embb)[i];
    reinterpret_cast<uint4*>(es)[c * 8 + (g ^ (c & 7))] = v;
    const ushort* pv = reinterpret_cast<const ushort*>(&v);
    float ss = 0.0f;
    #pragma unroll
    for (int e = 0; e < 8; ++e) { float f = b2f(pv[e]); ss = fmaf(f, f, ss); }
    ss += __shfl_xor(ss, 1);
    ss += __shfl_xor(ss, 2);
    ss += __shfl_xor(ss, 4);
    if ((i & 7) == 0) eel[c] = ss;
  }
  for (int i = tid; i < 512; i += 256) lhist[i] = 0;
  __syncthreads();

  const int rb = blockIdx.x * 256 + wid * 64;
  bf16x8 bz[4][2];
  float zz[4], best[4];
  int bi[4];
  #pragma unroll
  for (int rt = 0; rt < 4; ++rt) {
    const int r = rb + rt * 16 + l15;
    uint4 v0 = *reinterpret_cast<const uint4*>(zt + (size_t)r * 64 + l4 * 8);
    uint4 v1 = *reinterpret_cast<const uint4*>(zt + (size_t)r * 64 + 32 + l4 * 8);
    bz[rt][0] = __builtin_bit_cast(bf16x8, v0);
    bz[rt][1] = __builtin_bit_cast(bf16x8, v1);
    float s = 0.0f;
    const ushort* p0 = reinterpret_cast<const ushort*>(&v0);
    const ushort* p1 = reinterpret_cast<const ushort*>(&v1);
    #pragma unroll
    for (int e = 0; e < 8; ++e) {
      float f0 = b2f(p0[e]), f1 = b2f(p1[e]);
      s = fmaf(f0, f0, fmaf(f1, f1, s));
    }
    s += __shfl_xor(s, 16);
    s += __shfl_xor(s, 32);
    zz[rt] = s;
    best[rt] = 3.4e38f;
    bi[rt] = 0;
  }

  for (int ct = 0; ct < 32; ++ct) {
    const int c = ct * 16 + l15;
    bf16x8 a0 = __builtin_bit_cast(bf16x8, reinterpret_cast<const uint4*>(es)[
        c * 8 + (l4 ^ (c & 7))]);
    bf16x8 a1 = __builtin_bit_cast(bf16x8, reinterpret_cast<const uint4*>(es)[
        c * 8 + ((4 | l4) ^ (c & 7))]);
    #pragma unroll
    for (int rt = 0; rt < 4; ++rt) {
      f32x4 acc = {};
      acc = __builtin_amdgcn_mfma_f32_16x16x32_bf16(a0, bz[rt][0], acc, 0, 0, 0);
      acc = __builtin_amdgcn_mfma_f32_16x16x32_bf16(a1, bz[rt][1], acc, 0, 0, 0);
      #pragma unroll
      for (int rr = 0; rr < 4; ++rr) {
        int code = ct * 16 + l4 * 4 + rr;
        float d = eel[code] - 2.0f * acc[rr];
        if (d < best[rt] || (d == best[rt] && code < bi[rt])) { best[rt] = d; bi[rt] = code; }
      }
    }
  }
  float vsum = 0.0f;
  #pragma unroll
  for (int rt = 0; rt < 4; ++rt) {
    #pragma unroll
    for (int m = 16; m <= 32; m <<= 1) {
      float ob = __shfl_xor(best[rt], m);
      int oi = __shfl_xor(bi[rt], m);
      if (ob < best[rt] || (ob == best[rt] && oi < bi[rt])) { best[rt] = ob; bi[rt] = oi; }
    }
    if (l4 == 0) {
      idx[rb + rt * 16 + l15] = bi[rt];
      atomicAdd(&lhist[bi[rt]], 1);
      vsum += zz[rt] + best[rt];
    }
  }
  #pragma unroll
  for (int m = 1; m < 64; m <<= 1) vsum += __shfl_xor(vsum, m);
  if (lane == 0) atomicAdd(loss_accum, vsum);
  __syncthreads();
  for (int i = tid; i < 512; i += 256)
    if (lhist[i]) atomicAdd(&hist[i], lhist[i]);
}

__global__ __launch_bounds__(512)
void finalize(const int* __restrict__ hist, const float* __restrict__ loss_accum,
              float* __restrict__ out) {
  __shared__ float red[8];
  int tid = threadIdx.x;
  float avg = (float)hist[tid] * (1.0f / 65536.0f);
  float v = avg * logf(avg + 1e-10f);
  for (int off = 32; off > 0; off >>= 1) v += __shfl_down(v, off);
  if ((tid & 63) == 0) red[tid >> 6] = v;
  __syncthreads();
  if (tid == 0) {
    float s = 0.0f;
    for (int i = 0; i < 8; ++i) s += red[i];
    out[1048577] = expf(-s);
    out[0] = 1.25f * loss_accum[0] * (1.0f / (65536.0f * 64.0f));
  }
}

// ======================= launcher =======================
extern "C" void kernel_launch(void* const* d_in, const int* in_sizes, int n_in,
                              void* d_out, int out_size, void* d_ws, size_t ws_size,
                              hipStream_t stream) {
  (void)in_sizes; (void)n_in; (void)out_size; (void)ws_size;
  const float* x    = (const float*)d_in[0];
  const float* c1w  = (const float*)d_in[1];
  const float* c1b  = (const float*)d_in[2];
  const float* c2w  = (const float*)d_in[3];
  const float* c2b  = (const float*)d_in[4];
  const float* c3w  = (const float*)d_in[5];
  const float* c3b  = (const float*)d_in[6];
  const float* c4w  = (const float*)d_in[7];
  const float* c4b  = (const float*)d_in[8];
  const float* cfw  = (const float*)d_in[9];
  const float* cfb  = (const float*)d_in[10];
  const float* erw1 = (const float*)d_in[11];
  const float* erw2 = (const float*)d_in[12];
  const float* pqw  = (const float*)d_in[13];
  const float* pqb  = (const float*)d_in[14];
  const float* emb  = (const float*)d_in[15];
  const float* diw  = (const float*)d_in[16];
  const float* dib  = (const float*)d_in[17];
  const float* drw1 = (const float*)d_in[18];
  const float* drw2 = (const float*)d_in[19];
  const float* t0w  = (const float*)d_in[20];
  const float* t0b  = (const float*)d_in[21];
  const float* t1w  = (const float*)d_in[22];
  const float* t1b  = (const float*)d_in[23];
  const float* t2w  = (const float*)d_in[24];
  const float* t2b  = (const float*)d_in[25];
  const float* t3w  = (const float*)d_in[26];
  const float* t3b  = (const float*)d_in[27];

  char* wsb = (char*)d_ws;
  ushort* R0 = (ushort*)wsb;                           // ct1-out
  ushort* R1 = (ushort*)(wsb + 67108864);              // e2
  ushort* R2 = (ushort*)(wsb + 134217728);             // e3 ; later ct0-out
  ushort* R3 = (ushort*)(wsb + 0);                     // e4 / dec ping
  ushort* R4 = (ushort*)(wsb + 16777216);              // cf / dec pong
  ushort* R6 = (ushort*)(wsb + 37748736);              // zt (BT,64)
  ushort* WPu = (ushort*)(wsb + 167772160);
  ushort* wb_e2 = WPu + 0;
  ushort* wb_e3 = WPu + 32768;
  ushort* wb_e4 = WPu + 98304;
  ushort* wb_cf = WPu + 163840;
  ushort* wb_r1a = WPu + 212992;
  ushort* wb_r1b = WPu + 225280;
  ushort* wb_r2a = WPu + 237568;
  ushort* wb_r2b = WPu + 241664;
  ushort* wb_pq = WPu + 245760;
  ushort* wb_di = WPu + 253952;
  ushort* wb_d1a = WPu + 278528;
  ushort* wb_d1b = WPu + 290816;
  ushort* wb_d2a = WPu + 303104;
  ushort* wb_d2b = WPu + 307200;
  ushort* wb_t0 = WPu + 311296;
  ushort* wb_t1 = WPu + 376832;
  ushort* wb_t2 = WPu + 442368;
  ushort* wb_emb = WPu + 475136;
  char* fp = wsb + 167772160 + 1048576;
  int*   idxb  = (int*)(fp + 2048);
  int*   histb = (int*)(fp + 2048 + 262144);
  float* lossb = (float*)(fp + 2048 + 262144 + 2048);
  float* outp  = (float*)d_out;

  hipMemsetAsync(histb, 0, 512 * sizeof(int), stream);
  hipMemsetAsync(lossb, 0, sizeof(float), stream);

  PrepArgs pa{};
  int nw = 0, total = 0;
  auto addw = [&](const float* src, ushort* dst, int CO, int CI, int K,
                  int sco, int sci, int sk) {
    pa.tot[nw] = K * CO * CI; pa.src[nw] = src; pa.dst[nw] = dst;
    pa.ci[nw] = CI; pa.co[nw] = CO; pa.sco[nw] = sco; pa.sci[nw] = sci; pa.sk[nw] = sk;
    total += pa.tot[nw]; ++nw;
  };
  addw(c2w, wb_e2, 128, 64, 4, 256, 4, 1);
  addw(c3w, wb_e3, 128, 128, 4, 512, 4, 1);
  addw(c4w, wb_e4, 128, 128, 4, 512, 4, 1);
  addw(cfw, wb_cf, 128, 128, 3, 384, 3, 1);
  addw(erw1, wb_r1a, 32, 128, 3, 384, 3, 1);
  addw(erw1 + 12288, wb_r1b, 32, 128, 3, 384, 3, 1);
  addw(erw2, wb_r2a, 128, 32, 1, 32, 1, 1);
  addw(erw2 + 4096, wb_r2b, 128, 32, 1, 32, 1, 1);
  addw(pqw, wb_pq, 64, 128, 1, 128, 1, 1);
  addw(diw, wb_di, 128, 64, 3, 192, 3, 1);
  addw(drw1, wb_d1a, 32, 128, 3, 384, 3, 1);
  addw(drw1 + 12288, wb_d1b, 32, 128, 3, 384, 3, 1);
  addw(drw2, wb_d2a, 128, 32, 1, 32, 1, 1);
  addw(drw2 + 4096, wb_d2b, 128, 32, 1, 32, 1, 1);
  addw(t0w, wb_t0, 128, 128, 4, 4, 512, 1);
  addw(t1w, wb_t1, 128, 128, 4, 4, 512, 1);
  addw(t2w, wb_t2, 64, 128, 4, 4, 256, 1);
  addw(emb, wb_emb, 512, 64, 1, 64, 1, 1);
  pa.nw = nw;
  prep_all<<<(total + 255) / 256, 256, 0, stream>>>(pa, total);

  // ---- encoder ----
  enc12_mfma<<<4096, 256, 0, stream>>>(x, c1w, c1b, wb_e2, c2b, R1);
  conv_mfma<128, 128, 4, 2, true, false, 8, 4, 2><<<1024, 256, 0, stream>>>(R1, wb_e3, c3b, nullptr, R2, nullptr, 1024, 0, 1);
  conv_mfma<128, 128, 4, 2, true, false, 8, 4, 2><<<512, 256, 0, stream>>>(R2, wb_e4, c4b, nullptr, R3, nullptr, 512, 0, 1);
  conv_mfma<128, 128, 3, 1, true, false, 8, 2><<<512, 256, 0, stream>>>(R3, wb_cf, cfb, nullptr, R4, nullptr, 256, 0, 0);
  res_mfma<<<1024, 256, 0, stream>>>(R4, wb_r1a, wb_r2a, R3);
  res_mfma<<<1024, 256, 0, stream>>>(R3, wb_r1b, wb_r2b, R4);
  conv_mfma<128, 64, 1, 1, false, false, 8, 2><<<512, 256, 0, stream>>>(R4, wb_pq, pqb, nullptr, R6, nullptr, 256, 1, 0);
  // ---- VQ ----
  vq_mfma<<<256, 256, 0, stream>>>(R6, wb_emb, idxb, histb, lossb);
  finalize<<<1, 512, 0, stream>>>(histb, lossb, outp);
  // ---- decoder ----
  conv_mfma<64, 128, 3, 1, false, true, 8, 2><<<512, 256, 0, stream>>>(wb_emb, wb_di, dib, nullptr, R3, idxb, 256, 0, 0);
  res_mfma<<<1024, 256, 0, stream>>>(R3, wb_d1a, wb_d2a, R4);
  res_mfma<<<1024, 256, 0, stream>>>(R4, wb_d1b, wb_d2b, R3);
  convt_mfma<128><<<1024, 256, 0, stream>>>(R3, wb_t0, t0b, R2, 256, 1, 1);
  convt_mfma<128><<<2048, 256, 0, stream>>>(R2, wb_t1, t1b, R0, 512, 0, 1);
  ct23_mfma<<<4096, 256, 0, stream>>>(R0, wb_t2, t2b, t3w, t3b, outp + 1);
}

// Round 16
// 406.682 us; speedup vs baseline: 1.1238x; 1.1238x over previous
//
#include <hip/hip_runtime.h>

#define DEVI __device__ __forceinline__

typedef __bf16 bf16x8 __attribute__((ext_vector_type(8)));
typedef float f32x4 __attribute__((ext_vector_type(4)));

DEVI ushort f2b(float f) {            // f32 -> bf16 RNE
  uint b = __float_as_uint(f);
  uint r = (b + 0x7FFFu + ((b >> 16) & 1u)) >> 16;
  return (ushort)r;
}
DEVI float b2f(ushort u) { return __uint_as_float(((uint)u) << 16); }

// ======================= weight prep: all convs -> bf16 Wb[tap][co][ci] =======================
struct PrepArgs {
  int nw;
  int tot[20];
  const float* src[20];
  ushort* dst[20];
  int ci[20], co[20], sco[20], sci[20], sk[20];
};

__global__ __launch_bounds__(256)
void prep_all(PrepArgs a, int total) {
  int i = blockIdx.x * 256 + threadIdx.x;
  if (i >= total) return;
  int w = 0;
  while (i >= a.tot[w]) { i -= a.tot[w]; ++w; }
  const int li = i;
  const int CI = a.ci[w];
  int ciX = i % CI;
  int rest = i / CI;
  int coX = rest % a.co[w];
  int k = rest / a.co[w];
  a.dst[w][li] = f2b(a.src[w][coX * a.sco[w] + ciX * a.sci[w] + k * a.sk[w]]);
}

// ======================= fused enc1+enc2 (v2) =======================
__global__ __launch_bounds__(256)
void enc12_mfma(const float* __restrict__ x, const float* __restrict__ w1,
                const float* __restrict__ b1, const ushort* __restrict__ wb,
                const float* __restrict__ b2, ushort* __restrict__ out) {
  constexpr int CI = 64, CO = 128, K = 4, TT = 64;
  constexpr int SPAN = 2 * (TT - 1) + K;       // 130 e1 rows
  __shared__ __align__(16) ushort xs[SPAN * CI];
  __shared__ float xl[264];
  __shared__ float w1s[256];
  __shared__ float b1s[64];

  const int n = blockIdx.x >> 4;
  const int t0 = (blockIdx.x & 15) * TT;
  const int tid = threadIdx.x;
  const int wid = tid >> 6, lane = tid & 63;
  const int l15 = lane & 15, l4 = lane >> 4;

  const int t_in0 = 2 * t0 - 1;
  const int xw0 = 2 * t_in0 - 1;
  const float* xb = x + ((size_t)n << 12);

  for (int j = tid; j < 262; j += 256)
    xl[j] = xb[(xw0 + j + 8192) & 4095];
  if (tid < 256) w1s[tid] = w1[tid];
  if (tid < 64) b1s[tid] = b1[tid];
  __syncthreads();

  const int g = tid & 7;
  float4 wv[8];
  float bs[8];
  #pragma unroll
  for (int e = 0; e < 8; ++e) {
    wv[e] = *reinterpret_cast<const float4*>(&w1s[(g * 8 + e) * 4]);
    bs[e] = b1s[g * 8 + e];
  }
  #pragma unroll
  for (int it = 0; it < 5; ++it) {
    int t = it * 32 + (tid >> 3);
    if (t < SPAN) {
      float x0 = xl[2 * t], x1 = xl[2 * t + 1], x2 = xl[2 * t + 2], x3 = xl[2 * t + 3];
      uint pack[4];
      #pragma unroll
      for (int h = 0; h < 4; ++h) {
        float s0 = fmaf(wv[2 * h].x, x0, fmaf(wv[2 * h].y, x1,
                   fmaf(wv[2 * h].z, x2, fmaf(wv[2 * h].w, x3, bs[2 * h]))));
        float s1 = fmaf(wv[2 * h + 1].x, x0, fmaf(wv[2 * h + 1].y, x1,
                   fmaf(wv[2 * h + 1].z, x2, fmaf(wv[2 * h + 1].w, x3, bs[2 * h + 1]))));
        pack[h] = (uint)f2b(fmaxf(s0, 0.0f)) | ((uint)f2b(fmaxf(s1, 0.0f)) << 16);
      }
      *reinterpret_cast<uint4*>(&xs[t * CI + ((g ^ ((t >> 1) & 7)) * 8)]) =
          uint4{pack[0], pack[1], pack[2], pack[3]};
    }
  }
  __syncthreads();

  const int co_base = wid * 32;
  f32x4 acc[4][2] = {};
  for (int cc = 0; cc < 2; ++cc) {
    bf16x8 bk[K][2];
    #pragma unroll
    for (int k = 0; k < K; ++k)
      #pragma unroll
      for (int c = 0; c < 2; ++c)
        bk[k][c] = __builtin_bit_cast(bf16x8, *reinterpret_cast<const uint4*>(
            wb + (size_t)((k * CO + co_base + c * 16 + l15)) * CI + cc * 32 + l4 * 8));
    #pragma unroll
    for (int k = 0; k < K; ++k) {
      #pragma unroll
      for (int tt2 = 0; tt2 < 4; ++tt2) {
        int trow = 2 * (tt2 * 16 + l15) + k;
        int gg = cc * 4 + l4;
        bf16x8 afr = __builtin_bit_cast(bf16x8, *reinterpret_cast<const uint4*>(
            &xs[trow * CI + ((gg ^ ((trow >> 1) & 7)) * 8)]));
        #pragma unroll
        for (int c = 0; c < 2; ++c)
          acc[tt2][c] = __builtin_amdgcn_mfma_f32_16x16x32_bf16(afr, bk[k][c], acc[tt2][c], 0, 0, 0);
      }
    }
  }
  float bv[2];
  #pragma unroll
  for (int c = 0; c < 2; ++c) bv[c] = b2[co_base + c * 16 + l15];
  ushort* outb = out + (size_t)n * 1024 * CO;
  #pragma unroll
  for (int tt2 = 0; tt2 < 4; ++tt2)
    #pragma unroll
    for (int c = 0; c < 2; ++c)
      #pragma unroll
      for (int r = 0; r < 4; ++r) {
        int t = t0 + tt2 * 16 + 4 * l4 + r;
        int co = co_base + c * 16 + l15;
        outb[(size_t)t * CO + co] = f2b(fmaxf(acc[tt2][c][r] + bv[c], 0.0f));
      }
}

// ======================= generalized MFMA forward conv (optionally ci-chunked) ===============
template<int CI, int CO, int K, int S, bool CIRC, bool GATHER, int NT, int WAVES_CO,
         int NCHUNK = 1>
__global__ __launch_bounds__(256)
void conv_mfma(const ushort* __restrict__ in, const ushort* __restrict__ wb,
               const float* __restrict__ bias, const ushort* __restrict__ resid,
               ushort* __restrict__ out, const int* __restrict__ gidx,
               int Tin, int in_relu, int out_relu) {
  constexpr int PAD = (K > 1) ? 1 : 0;
  constexpr int TT = NT * 16;
  constexpr int SPAN = S * (TT - 1) + K;
  constexpr int CICH = CI / NCHUNK;
  constexpr int CIGc = CICH / 8;
  constexpr int COT = CO / 16;
  constexpr int WCOT = COT / WAVES_CO;
  constexpr int WAVES_T = 4 / WAVES_CO;
  constexpr int WTT = NT / WAVES_T;
  constexpr int KSH = (S == 2) ? 1 : 0;
  static_assert(CICH % 32 == 0 && COT % WAVES_CO == 0 && NT % WAVES_T == 0, "");

  __shared__ __align__(16) ushort xs[SPAN * CICH];

  const int Tout = Tin / S;
  const int tilesPerB = Tout / TT;
  const int n = blockIdx.x / tilesPerB;
  const int t0 = (blockIdx.x % tilesPerB) * TT;
  const int tid = threadIdx.x;
  const int wid = tid >> 6, lane = tid & 63;
  const int l15 = lane & 15, l4 = lane >> 4;

  const int t_in0 = S * t0 - PAD;
  const ushort* inb = GATHER ? in : in + (size_t)n * Tin * CI;

  const int wco = wid % WAVES_CO;
  const int wt = wid / WAVES_CO;
  const int co_base = wco * WCOT * 16;
  const int t_base = wt * WTT * 16;

  f32x4 acc[WTT][WCOT] = {};

  for (int h = 0; h < NCHUNK; ++h) {
    if (h) __syncthreads();
    for (int i = tid; i < SPAN * CIGc; i += 256) {
      int t = i / CIGc, g = i - (i / CIGc) * CIGc;
      int tg = t_in0 + t;
      uint4 v;
      if (CIRC) {
        tg = (tg < 0) ? tg + Tin : (tg >= Tin ? tg - Tin : tg);
        v = *reinterpret_cast<const uint4*>(inb + (size_t)tg * CI + h * CICH + g * 8);
      } else if (GATHER) {
        if ((unsigned)tg < (unsigned)Tin) {
          int id = gidx[n * Tin + tg];
          v = *reinterpret_cast<const uint4*>(inb + (size_t)id * CI + h * CICH + g * 8);
        } else
          v = uint4{0, 0, 0, 0};
      } else {
        if ((unsigned)tg < (unsigned)Tin)
          v = *reinterpret_cast<const uint4*>(inb + (size_t)tg * CI + h * CICH + g * 8);
        else
          v = uint4{0, 0, 0, 0};
      }
      if (in_relu) {
        ushort* pv = reinterpret_cast<ushort*>(&v);
        #pragma unroll
        for (int e = 0; e < 8; ++e) pv[e] = (pv[e] & 0x8000) ? 0 : pv[e];
      }
      *reinterpret_cast<uint4*>(&xs[t * CICH + ((g ^ ((t >> KSH) & (CIGc - 1))) * 8)]) = v;
    }
    __syncthreads();

    for (int cc = 0; cc < CICH / 32; ++cc) {
      const int ccg = h * (CICH / 32) + cc;
      bf16x8 bk[K][WCOT];
      #pragma unroll
      for (int k = 0; k < K; ++k)
        #pragma unroll
        for (int c = 0; c < WCOT; ++c)
          bk[k][c] = __builtin_bit_cast(bf16x8, *reinterpret_cast<const uint4*>(
              wb + (size_t)((k * CO + co_base + c * 16 + l15)) * CI + ccg * 32 + l4 * 8));
      #pragma unroll
      for (int k = 0; k < K; ++k) {
        #pragma unroll
        for (int tt2 = 0; tt2 < WTT; ++tt2) {
          int trow = S * (t_base + tt2 * 16 + l15) + k;
          int g = cc * 4 + l4;
          bf16x8 afr = __builtin_bit_cast(bf16x8, *reinterpret_cast<const uint4*>(
              &xs[trow * CICH + ((g ^ ((trow >> KSH) & (CIGc - 1))) * 8)]));
          #pragma unroll
          for (int c = 0; c < WCOT; ++c)
            acc[tt2][c] = __builtin_amdgcn_mfma_f32_16x16x32_bf16(afr, bk[k][c], acc[tt2][c], 0, 0, 0);
        }
      }
    }
  }

  float bv[WCOT];
  #pragma unroll
  for (int c = 0; c < WCOT; ++c)
    bv[c] = bias ? bias[co_base + c * 16 + l15] : 0.0f;
  ushort* outb = out + (size_t)n * Tout * CO;
  const ushort* resb = resid ? resid + (size_t)n * Tout * CO : nullptr;
  #pragma unroll
  for (int tt2 = 0; tt2 < WTT; ++tt2)
    #pragma unroll
    for (int c = 0; c < WCOT; ++c)
      #pragma unroll
      for (int r = 0; r < 4; ++r) {
        int t = t0 + t_base + tt2 * 16 + 4 * l4 + r;
        int co = co_base + c * 16 + l15;
        float v = acc[tt2][c][r] + bv[c];
        if (resb) v += b2f(resb[(size_t)t * CO + co]);
        if (out_relu) v = fmaxf(v, 0.0f);
        outb[(size_t)t * CO + co] = f2b(v);
      }
}

// ======================= fused residual layer (hs aliased into xs) =======================
__global__ __launch_bounds__(256)
void res_mfma(const ushort* __restrict__ in, const ushort* __restrict__ wb1,
              const ushort* __restrict__ wb2, ushort* __restrict__ out) {
  constexpr int CI = 128, CIG = 16;
  constexpr int TT = 64, SPAN = 66, Tin = 256;
  __shared__ __align__(16) ushort xs[SPAN * CI];
  ushort* hs = xs;
  const int n = blockIdx.x >> 2;
  const int t0 = (blockIdx.x & 3) * TT;
  const int tid = threadIdx.x;
  const int wid = tid >> 6, lane = tid & 63;
  const int l15 = lane & 15, l4 = lane >> 4;
  const int t_in0 = t0 - 1;
  const ushort* inb = in + (size_t)n * Tin * CI;

  for (int i = tid; i < SPAN * CIG; i += 256) {
    int t = i >> 4, g = i & 15;
    int tg = t_in0 + t;
    tg = (tg < 0) ? tg + Tin : (tg >= Tin ? tg - Tin : tg);
    uint4 v = *reinterpret_cast<const uint4*>(inb + (size_t)tg * CI + g * 8);
    ushort* pv = reinterpret_cast<ushort*>(&v);
    #pragma unroll
    for (int e = 0; e < 8; ++e) pv[e] = (pv[e] & 0x8000) ? 0 : pv[e];
    *reinterpret_cast<uint4*>(&xs[t * CI + ((g ^ (t & 15)) * 8)]) = v;
  }
  __syncthreads();

  f32x4 acc1[2] = {};
  for (int cc = 0; cc < 4; ++cc)
    #pragma unroll
    for (int k = 0; k < 3; ++k) {
      bf16x8 bfr[2];
      #pragma unroll
      for (int c = 0; c < 2; ++c)
        bfr[c] = __builtin_bit_cast(bf16x8, *reinterpret_cast<const uint4*>(
            wb1 + (size_t)((k * 32 + c * 16 + l15)) * CI + cc * 32 + l4 * 8));
      int trow = wid * 16 + l15 + k;
      int g = cc * 4 + l4;
      bf16x8 afr = __builtin_bit_cast(bf16x8, *reinterpret_cast<const uint4*>(
          &xs[trow * CI + ((g ^ (trow & 15)) * 8)]));
      acc1[0] = __builtin_amdgcn_mfma_f32_16x16x32_bf16(afr, bfr[0], acc1[0], 0, 0, 0);
      acc1[1] = __builtin_amdgcn_mfma_f32_16x16x32_bf16(afr, bfr[1], acc1[1], 0, 0, 0);
    }
  __syncthreads();
  #pragma unroll
  for (int c = 0; c < 2; ++c)
    #pragma unroll
    for (int r = 0; r < 4; ++r) {
      float v = acc1[c][r];
      hs[(wid * 16 + l4 * 4 + r) * 40 + c * 16 + l15] = (v > 0.0f) ? f2b(v) : (ushort)0;
    }
  __syncthreads();

  {
    bf16x8 afr = *reinterpret_cast<const bf16x8*>(&hs[(wid * 16 + l15) * 40 + l4 * 8]);
    f32x4 acc[8];
    #pragma unroll
    for (int c = 0; c < 8; ++c) {
      bf16x8 bfr = __builtin_bit_cast(bf16x8, *reinterpret_cast<const uint4*>(
          wb2 + (size_t)(c * 16 + l15) * 32 + l4 * 8));
      f32x4 z = {};
      acc[c] = __builtin_amdgcn_mfma_f32_16x16x32_bf16(afr, bfr, z, 0, 0, 0);
    }
    ushort* outb = out + (size_t)n * Tin * CI;
    #pragma unroll
    for (int c = 0; c < 8; ++c)
      #pragma unroll
      for (int r = 0; r < 4; ++r) {
        int t = t0 + wid * 16 + l4 * 4 + r;
        int co = c * 16 + l15;
        float v = acc[c][r] + b2f(inb[(size_t)t * CI + co]);
        outb[(size_t)t * CI + co] = f2b(v);
      }
  }
}

// ======================= MFMA transposed conv k=4 s=2 p=1 (CI=128) =======================
template<int CO>
__global__ __launch_bounds__(256)
void convt_mfma(const ushort* __restrict__ in, const ushort* __restrict__ wb,
                const float* __restrict__ bias, ushort* __restrict__ out,
                int Tin, int in_relu, int out_relu) {
  constexpr int CI = 128, CIG = 16;
  constexpr int NT = 4, TT = 64;
  constexpr int SPAN = TT + 2;
  constexpr int COT = CO / 16;
  constexpr int WCOT = (COT + 3) / 4;
  constexpr int WAVES_CO = COT / WCOT;
  constexpr int WTT = NT;

  __shared__ __align__(16) ushort xs[SPAN * CI];

  const int Tout = 2 * Tin;
  const int tilesPerB = Tin / TT;
  const int n = blockIdx.x / tilesPerB;
  const int tp0 = (blockIdx.x % tilesPerB) * TT;
  const int tid = threadIdx.x;
  const int wid = tid >> 6, lane = tid & 63;
  const int l15 = lane & 15, l4 = lane >> 4;

  const int t_in0 = tp0 - 1;
  const ushort* inb = in + (size_t)n * Tin * CI;
  for (int i = tid; i < SPAN * CIG; i += 256) {
    int t = i >> 4, g = i & 15;
    int tg = t_in0 + t;
    uint4 v;
    if ((unsigned)tg < (unsigned)Tin)
      v = *reinterpret_cast<const uint4*>(inb + (size_t)tg * CI + g * 8);
    else
      v = uint4{0, 0, 0, 0};
    if (in_relu) {
      ushort* pv = reinterpret_cast<ushort*>(&v);
      #pragma unroll
      for (int e = 0; e < 8; ++e) pv[e] = (pv[e] & 0x8000) ? 0 : pv[e];
    }
    *reinterpret_cast<uint4*>(&xs[t * CI + ((g ^ (t & 15)) * 8)]) = v;
  }
  __syncthreads();

  const int wco = wid % WAVES_CO;
  const int co_base = wco * WCOT * 16;

  f32x4 accE[WTT][WCOT] = {};
  f32x4 accO[WTT][WCOT] = {};

  for (int cc = 0; cc < 4; ++cc) {
    bf16x8 bk[4][WCOT];
    #pragma unroll
    for (int k = 0; k < 4; ++k)
      #pragma unroll
      for (int c = 0; c < WCOT; ++c)
        bk[k][c] = __builtin_bit_cast(bf16x8, *reinterpret_cast<const uint4*>(
            wb + (size_t)((k * CO + co_base + c * 16 + l15)) * CI + cc * 32 + l4 * 8));
    #pragma unroll
    for (int tt2 = 0; tt2 < WTT; ++tt2) {
      int lt = tt2 * 16 + l15 + 1;
      int g = cc * 4 + l4;
      bf16x8 a0 = __builtin_bit_cast(bf16x8, *reinterpret_cast<const uint4*>(
          &xs[lt * CI + ((g ^ (lt & 15)) * 8)]));
      bf16x8 am = __builtin_bit_cast(bf16x8, *reinterpret_cast<const uint4*>(
          &xs[(lt - 1) * CI + ((g ^ ((lt - 1) & 15)) * 8)]));
      bf16x8 ap = __builtin_bit_cast(bf16x8, *reinterpret_cast<const uint4*>(
          &xs[(lt + 1) * CI + ((g ^ ((lt + 1) & 15)) * 8)]));
      #pragma unroll
      for (int c = 0; c < WCOT; ++c) {
        accE[tt2][c] = __builtin_amdgcn_mfma_f32_16x16x32_bf16(a0, bk[1][c], accE[tt2][c], 0, 0, 0);
        accE[tt2][c] = __builtin_amdgcn_mfma_f32_16x16x32_bf16(am, bk[3][c], accE[tt2][c], 0, 0, 0);
        accO[tt2][c] = __builtin_amdgcn_mfma_f32_16x16x32_bf16(ap, bk[0][c], accO[tt2][c], 0, 0, 0);
        accO[tt2][c] = __builtin_amdgcn_mfma_f32_16x16x32_bf16(a0, bk[2][c], accO[tt2][c], 0, 0, 0);
      }
    }
  }

  float bv[WCOT];
  #pragma unroll
  for (int c = 0; c < WCOT; ++c) bv[c] = bias[co_base + c * 16 + l15];
  ushort* outb = out + (size_t)n * Tout * CO;
  #pragma unroll
  for (int tt2 = 0; tt2 < WTT; ++tt2)
    #pragma unroll
    for (int c = 0; c < WCOT; ++c)
      #pragma unroll
      for (int r = 0; r < 4; ++r) {
        int tp = tp0 + tt2 * 16 + 4 * l4 + r;
        int co = co_base + c * 16 + l15;
        float vE = accE[tt2][c][r] + bv[c];
        float vO = accO[tt2][c][r] + bv[c];
        if (out_relu) { vE = fmaxf(vE, 0.0f); vO = fmaxf(vO, 0.0f); }
        outb[(size_t)(2 * tp) * CO + co] = f2b(vE);
        outb[(size_t)(2 * tp + 1) * CO + co] = f2b(vO);
      }
}

// ======================= fused ct2+ct3 (TT=64) =======================
// ys transposed [j][66] aliased onto xs; conflict-free; 18.2 KB LDS.
__global__ __launch_bounds__(256)
void ct23_mfma(const ushort* __restrict__ in, const ushort* __restrict__ wb,
               const float* __restrict__ bias, const float* __restrict__ w3,
               const float* __restrict__ b3, float* __restrict__ out) {
  constexpr int CI = 128, CO = 64, CIG = 16;
  constexpr int TT = 64, SPAN = 66, Tin = 1024;
  __shared__ __align__(16) ushort buf[8580];
  __shared__ float2 w3p[2][64];
  ushort* xs = buf;
  ushort* ys = buf;

  const int n = blockIdx.x >> 4;
  const int tp0 = (blockIdx.x & 15) * TT;
  const int tid = threadIdx.x;
  const int wid = tid >> 6, lane = tid & 63;
  const int l15 = lane & 15, l4 = lane >> 4;
  const int t_in0 = tp0 - 1;
  const ushort* inb = in + (size_t)n * Tin * CI;

  if (tid < 128) {
    int parity = tid >> 6, ci = tid & 63;
    w3p[parity][ci] = parity
        ? float2{w3[ci * 4 + 0], w3[ci * 4 + 2]}
        : float2{w3[ci * 4 + 1], w3[ci * 4 + 3]};
  }
  for (int i = tid; i < SPAN * CIG; i += 256) {
    int t = i >> 4, g = i & 15;
    int tg = t_in0 + t;
    uint4 v;
    if ((unsigned)tg < (unsigned)Tin)
      v = *reinterpret_cast<const uint4*>(inb + (size_t)tg * CI + g * 8);
    else
      v = uint4{0, 0, 0, 0};
    *reinterpret_cast<uint4*>(&xs[t * CI + ((g ^ (t & 15)) * 8)]) = v;
  }
  __syncthreads();

  const int co = wid * 16 + l15;
  f32x4 accE[4] = {}, accO[4] = {};
  f32x4 hO = {}, hE = {};

  for (int cc = 0; cc < 4; ++cc) {
    bf16x8 bk[4];
    #pragma unroll
    for (int k = 0; k < 4; ++k)
      bk[k] = __builtin_bit_cast(bf16x8, *reinterpret_cast<const uint4*>(
          wb + (size_t)((k * CO + co)) * CI + cc * 32 + l4 * 8));
    const int g = cc * 4 + l4;
    auto rd = [&](int lt) -> bf16x8 {
      return __builtin_bit_cast(bf16x8, *reinterpret_cast<const uint4*>(
          &xs[lt * CI + ((g ^ (lt & 15)) * 8)]));
    };
    #pragma unroll
    for (int tt2 = 0; tt2 < 4; ++tt2) {
      int lt = tt2 * 16 + l15 + 1;
      bf16x8 a0 = rd(lt), am = rd(lt - 1), ap = rd(lt + 1);
      accE[tt2] = __builtin_amdgcn_mfma_f32_16x16x32_bf16(a0, bk[1], accE[tt2], 0, 0, 0);
      accE[tt2] = __builtin_amdgcn_mfma_f32_16x16x32_bf16(am, bk[3], accE[tt2], 0, 0, 0);
      accO[tt2] = __builtin_amdgcn_mfma_f32_16x16x32_bf16(ap, bk[0], accO[tt2], 0, 0, 0);
      accO[tt2] = __builtin_amdgcn_mfma_f32_16x16x32_bf16(a0, bk[2], accO[tt2], 0, 0, 0);
    }
    bf16x8 h0 = rd(0), h1 = rd(1), h64 = rd(64), h65 = rd(65);
    hO = __builtin_amdgcn_mfma_f32_16x16x32_bf16(h1, bk[0], hO, 0, 0, 0);
    hO = __builtin_amdgcn_mfma_f32_16x16x32_bf16(h0, bk[2], hO, 0, 0, 0);
    hE = __builtin_amdgcn_mfma_f32_16x16x32_bf16(h65, bk[1], hE, 0, 0, 0);
    hE = __builtin_amdgcn_mfma_f32_16x16x32_bf16(h64, bk[3], hE, 0, 0, 0);
  }
  __syncthreads();

  const float bv = bias[co];
  #pragma unroll
  for (int tt2 = 0; tt2 < 4; ++tt2)
    #pragma unroll
    for (int r = 0; r < 4; ++r) {
      int m = tt2 * 16 + 4 * l4 + r;
      ys[(2 * m + 1) * 66 + co] = f2b(fmaxf(accE[tt2][r] + bv, 0.0f));
      ys[(2 * m + 2) * 66 + co] = f2b(fmaxf(accO[tt2][r] + bv, 0.0f));
    }
  if (l4 == 0) {
    ys[co]            = (tp0 == 0) ? (ushort)0 : f2b(fmaxf(hO[0] + bv, 0.0f));
    ys[129 * 66 + co] = (tp0 + TT == Tin) ? (ushort)0 : f2b(fmaxf(hE[0] + bv, 0.0f));
  }
  __syncthreads();

  const int o = 4 * tp0 + tid;
  const int odd = tid & 1;
  const int ha = (tid + odd) >> 1;
  const ushort* ra = &ys[(ha + 1) * 66];
  const ushort* rb = &ys[ha * 66];
  const float2* wp = w3p[odd];
  float s = b3[0];
  #pragma unroll
  for (int c = 0; c < 32; ++c) {
    uint va = *reinterpret_cast<const uint*>(ra + 2 * c);
    uint vb = *reinterpret_cast<const uint*>(rb + 2 * c);
    float2 w0 = wp[2 * c], w1 = wp[2 * c + 1];
    s = fmaf(w0.x, __uint_as_float(va << 16), s);
    s = fmaf(w1.x, __uint_as_float(va & 0xFFFF0000u), s);
    s = fmaf(w0.y, __uint_as_float(vb << 16), s);
    s = fmaf(w1.y, __uint_as_float(vb & 0xFFFF0000u), s);
  }
  out[(size_t)n * 4096 + o] = s;
}

// ======================= VQ =======================
__global__ __launch_bounds__(256)
void vq_mfma(const ushort* __restrict__ zt, const ushort* __restrict__ embb,
             int* __restrict__ idx, int* __restrict__ hist,
             float* __restrict__ loss_accum) {
  __shared__ __align__(16) ushort es[512 * 64];
  __shared__ float eel[512];
  __shared__ int lhist[512];
  const int tid = threadIdx.x;
  const int wid = tid >> 6, lane = tid & 63;
  const int l15 = lane & 15, l4 = lane >> 4;

  for (int i = tid; i < 512 * 8; i += 256) {
    int c = i >> 3, g = i & 7;
    uint4 v = reinterpret_cast<const uint4*>(embb)[i];
    reinterpret_cast<uint4*>(es)[c * 8 + (g ^ (c & 7))] = v;
    const ushort* pv = reinterpret_cast<const ushort*>(&v);
    float ss = 0.0f;
    #pragma unroll
    for (int e = 0; e < 8; ++e) { float f = b2f(pv[e]); ss = fmaf(f, f, ss); }
    ss += __shfl_xor(ss, 1);
    ss += __shfl_xor(ss, 2);
    ss += __shfl_xor(ss, 4);
    if ((i & 7) == 0) eel[c] = ss;
  }
  for (int i = tid; i < 512; i += 256) lhist[i] = 0;
  __syncthreads();

  const int rb = blockIdx.x * 256 + wid * 64;
  bf16x8 bz[4][2];
  float zz[4], best[4];
  int bi[4];
  #pragma unroll
  for (int rt = 0; rt < 4; ++rt) {
    const int r = rb + rt * 16 + l15;
    uint4 v0 = *reinterpret_cast<const uint4*>(zt + (size_t)r * 64 + l4 * 8);
    uint4 v1 = *reinterpret_cast<const uint4*>(zt + (size_t)r * 64 + 32 + l4 * 8);
    bz[rt][0] = __builtin_bit_cast(bf16x8, v0);
    bz[rt][1] = __builtin_bit_cast(bf16x8, v1);
    float s = 0.0f;
    const ushort* p0 = reinterpret_cast<const ushort*>(&v0);
    const ushort* p1 = reinterpret_cast<const ushort*>(&v1);
    #pragma unroll
    for (int e = 0; e < 8; ++e) {
      float f0 = b2f(p0[e]), f1 = b2f(p1[e]);
      s = fmaf(f0, f0, fmaf(f1, f1, s));
    }
    s += __shfl_xor(s, 16);
    s += __shfl_xor(s, 32);
    zz[rt] = s;
    best[rt] = 3.4e38f;
    bi[rt] = 0;
  }

  for (int ct = 0; ct < 32; ++ct) {
    const int c = ct * 16 + l15;
    bf16x8 a0 = __builtin_bit_cast(bf16x8, reinterpret_cast<const uint4*>(es)[
        c * 8 + (l4 ^ (c & 7))]);
    bf16x8 a1 = __builtin_bit_cast(bf16x8, reinterpret_cast<const uint4*>(es)[
        c * 8 + ((4 | l4) ^ (c & 7))]);
    #pragma unroll
    for (int rt = 0; rt < 4; ++rt) {
      f32x4 acc = {};
      acc = __builtin_amdgcn_mfma_f32_16x16x32_bf16(a0, bz[rt][0], acc, 0, 0, 0);
      acc = __builtin_amdgcn_mfma_f32_16x16x32_bf16(a1, bz[rt][1], acc, 0, 0, 0);
      #pragma unroll
      for (int rr = 0; rr < 4; ++rr) {
        int code = ct * 16 + l4 * 4 + rr;
        float d = eel[code] - 2.0f * acc[rr];
        if (d < best[rt] || (d == best[rt] && code < bi[rt])) { best[rt] = d; bi[rt] = code; }
      }
    }
  }
  float vsum = 0.0f;
  #pragma unroll
  for (int rt = 0; rt < 4; ++rt) {
    #pragma unroll
    for (int m = 16; m <= 32; m <<= 1) {
      float ob = __shfl_xor(best[rt], m);
      int oi = __shfl_xor(bi[rt], m);
      if (ob < best[rt] || (ob == best[rt] && oi < bi[rt])) { best[rt] = ob; bi[rt] = oi; }
    }
    if (l4 == 0) {
      idx[rb + rt * 16 + l15] = bi[rt];
      atomicAdd(&lhist[bi[rt]], 1);
      vsum += zz[rt] + best[rt];
    }
  }
  #pragma unroll
  for (int m = 1; m < 64; m <<= 1) vsum += __shfl_xor(vsum, m);
  if (lane == 0) atomicAdd(loss_accum, vsum);
  __syncthreads();
  for (int i = tid; i < 512; i += 256)
    if (lhist[i]) atomicAdd(&hist[i], lhist[i]);
}

__global__ __launch_bounds__(512)
void finalize(const int* __restrict__ hist, const float* __restrict__ loss_accum,
              float* __restrict__ out) {
  __shared__ float red[8];
  int tid = threadIdx.x;
  float avg = (float)hist[tid] * (1.0f / 65536.0f);
  float v = avg * logf(avg + 1e-10f);
  for (int off = 32; off > 0; off >>= 1) v += __shfl_down(v, off);
  if ((tid & 63) == 0) red[tid >> 6] = v;
  __syncthreads();
  if (tid == 0) {
    float s = 0.0f;
    for (int i = 0; i < 8; ++i) s += red[i];
    out[1048577] = expf(-s);
    out[0] = 1.25f * loss_accum[0] * (1.0f / (65536.0f * 64.0f));
  }
}

// ======================= launcher =======================
extern "C" void kernel_launch(void* const* d_in, const int* in_sizes, int n_in,
                              void* d_out, int out_size, void* d_ws, size_t ws_size,
                              hipStream_t stream) {
  (void)in_sizes; (void)n_in; (void)out_size; (void)ws_size;
  const float* x    = (const float*)d_in[0];
  const float* c1w  = (const float*)d_in[1];
  const float* c1b  = (const float*)d_in[2];
  const float* c2w  = (const float*)d_in[3];
  const float* c2b  = (const float*)d_in[4];
  const float* c3w  = (const float*)d_in[5];
  const float* c3b  = (const float*)d_in[6];
  const float* c4w  = (const float*)d_in[7];
  const float* c4b  = (const float*)d_in[8];
  const float* cfw  = (const float*)d_in[9];
  const float* cfb  = (const float*)d_in[10];
  const float* erw1 = (const float*)d_in[11];
  const float* erw2 = (const float*)d_in[12];
  const float* pqw  = (const float*)d_in[13];
  const float* pqb  = (const float*)d_in[14];
  const float* emb  = (const float*)d_in[15];
  const float* diw  = (const float*)d_in[16];
  const float* dib  = (const float*)d_in[17];
  const float* drw1 = (const float*)d_in[18];
  const float* drw2 = (const float*)d_in[19];
  const float* t0w  = (const float*)d_in[20];
  const float* t0b  = (const float*)d_in[21];
  const float* t1w  = (const float*)d_in[22];
  const float* t1b  = (const float*)d_in[23];
  const float* t2w  = (const float*)d_in[24];
  const float* t2b  = (const float*)d_in[25];
  const float* t3w  = (const float*)d_in[26];
  const float* t3b  = (const float*)d_in[27];

  char* wsb = (char*)d_ws;
  ushort* R0 = (ushort*)wsb;                           // ct1-out
  ushort* R1 = (ushort*)(wsb + 67108864);              // e2
  ushort* R2 = (ushort*)(wsb + 134217728);             // e3 ; later ct0-out
  ushort* R3 = (ushort*)(wsb + 0);                     // e4 / dec ping
  ushort* R4 = (ushort*)(wsb + 16777216);              // cf / dec pong
  ushort* R6 = (ushort*)(wsb + 37748736);              // zt (BT,64)
  ushort* WPu = (ushort*)(wsb + 167772160);
  ushort* wb_e2 = WPu + 0;
  ushort* wb_e3 = WPu + 32768;
  ushort* wb_e4 = WPu + 98304;
  ushort* wb_cf = WPu + 163840;
  ushort* wb_r1a = WPu + 212992;
  ushort* wb_r1b = WPu + 225280;
  ushort* wb_r2a = WPu + 237568;
  ushort* wb_r2b = WPu + 241664;
  ushort* wb_pq = WPu + 245760;
  ushort* wb_di = WPu + 253952;
  ushort* wb_d1a = WPu + 278528;
  ushort* wb_d1b = WPu + 290816;
  ushort* wb_d2a = WPu + 303104;
  ushort* wb_d2b = WPu + 307200;
  ushort* wb_t0 = WPu + 311296;
  ushort* wb_t1 = WPu + 376832;
  ushort* wb_t2 = WPu + 442368;
  ushort* wb_emb = WPu + 475136;
  char* fp = wsb + 167772160 + 1048576;
  int*   idxb  = (int*)(fp + 2048);
  int*   histb = (int*)(fp + 2048 + 262144);
  float* lossb = (float*)(fp + 2048 + 262144 + 2048);
  float* outp  = (float*)d_out;

  hipMemsetAsync(histb, 0, 512 * sizeof(int), stream);
  hipMemsetAsync(lossb, 0, sizeof(float), stream);

  PrepArgs pa{};
  int nw = 0, total = 0;
  auto addw = [&](const float* src, ushort* dst, int CO, int CI, int K,
                  int sco, int sci, int sk) {
    pa.tot[nw] = K * CO * CI; pa.src[nw] = src; pa.dst[nw] = dst;
    pa.ci[nw] = CI; pa.co[nw] = CO; pa.sco[nw] = sco; pa.sci[nw] = sci; pa.sk[nw] = sk;
    total += pa.tot[nw]; ++nw;
  };
  addw(c2w, wb_e2, 128, 64, 4, 256, 4, 1);
  addw(c3w, wb_e3, 128, 128, 4, 512, 4, 1);
  addw(c4w, wb_e4, 128, 128, 4, 512, 4, 1);
  addw(cfw, wb_cf, 128, 128, 3, 384, 3, 1);
  addw(erw1, wb_r1a, 32, 128, 3, 384, 3, 1);
  addw(erw1 + 12288, wb_r1b, 32, 128, 3, 384, 3, 1);
  addw(erw2, wb_r2a, 128, 32, 1, 32, 1, 1);
  addw(erw2 + 4096, wb_r2b, 128, 32, 1, 32, 1, 1);
  addw(pqw, wb_pq, 64, 128, 1, 128, 1, 1);
  addw(diw, wb_di, 128, 64, 3, 192, 3, 1);
  addw(drw1, wb_d1a, 32, 128, 3, 384, 3, 1);
  addw(drw1 + 12288, wb_d1b, 32, 128, 3, 384, 3, 1);
  addw(drw2, wb_d2a, 128, 32, 1, 32, 1, 1);
  addw(drw2 + 4096, wb_d2b, 128, 32, 1, 32, 1, 1);
  addw(t0w, wb_t0, 128, 128, 4, 4, 512, 1);
  addw(t1w, wb_t1, 128, 128, 4, 4, 512, 1);
  addw(t2w, wb_t2, 64, 128, 4, 4, 256, 1);
  addw(emb, wb_emb, 512, 64, 1, 64, 1, 1);
  pa.nw = nw;
  prep_all<<<(total + 255) / 256, 256, 0, stream>>>(pa, total);

  // ---- encoder ----
  enc12_mfma<<<4096, 256, 0, stream>>>(x, c1w, c1b, wb_e2, c2b, R1);
  conv_mfma<128, 128, 4, 2, true, false, 8, 4, 2><<<1024, 256, 0, stream>>>(R1, wb_e3, c3b, nullptr, R2, nullptr, 1024, 0, 1);
  conv_mfma<128, 128, 4, 2, true, false, 8, 4, 2><<<512, 256, 0, stream>>>(R2, wb_e4, c4b, nullptr, R3, nullptr, 512, 0, 1);
  conv_mfma<128, 128, 3, 1, true, false, 8, 2><<<512, 256, 0, stream>>>(R3, wb_cf, cfb, nullptr, R4, nullptr, 256, 0, 0);
  res_mfma<<<1024, 256, 0, stream>>>(R4, wb_r1a, wb_r2a, R3);
  res_mfma<<<1024, 256, 0, stream>>>(R3, wb_r1b, wb_r2b, R4);
  conv_mfma<128, 64, 1, 1, false, false, 8, 2><<<512, 256, 0, stream>>>(R4, wb_pq, pqb, nullptr, R6, nullptr, 256, 1, 0);
  // ---- VQ ----
  vq_mfma<<<256, 256, 0, stream>>>(R6, wb_emb, idxb, histb, lossb);
  finalize<<<1, 512, 0, stream>>>(histb, lossb, outp);
  // ---- decoder ----
  conv_mfma<64, 128, 3, 1, false, true, 8, 2><<<512, 256, 0, stream>>>(wb_emb, wb_di, dib, nullptr, R3, idxb, 256, 0, 0);
  res_mfma<<<1024, 256, 0, stream>>>(R3, wb_d1a, wb_d2a, R4);
  res_mfma<<<1024, 256, 0, stream>>>(R4, wb_d1b, wb_d2b, R3);
  convt_mfma<128><<<1024, 256, 0, stream>>>(R3, wb_t0, t0b, R2, 256, 1, 1);
  convt_mfma<128><<<2048, 256, 0, stream>>>(R2, wb_t1, t1b, R0, 512, 0, 1);
  ct23_mfma<<<4096, 256, 0, stream>>>(R0, wb_t2, t2b, t3w, t3b, outp + 1);
}

// Round 17
// 405.926 us; speedup vs baseline: 1.1259x; 1.0019x over previous
//
#include <hip/hip_runtime.h>

#define DEVI __device__ __forceinline__

typedef __bf16 bf16x8 __attribute__((ext_vector_type(8)));
typedef float f32x4 __attribute__((ext_vector_type(4)));

DEVI ushort f2b(float f) {            // f32 -> bf16 RNE
  uint b = __float_as_uint(f);
  uint r = (b + 0x7FFFu + ((b >> 16) & 1u)) >> 16;
  return (ushort)r;
}
DEVI float b2f(ushort u) { return __uint_as_float(((uint)u) << 16); }

// ======================= weight prep: all convs -> bf16 Wb[tap][co][ci] =======================
struct PrepArgs {
  int nw;
  int tot[20];
  const float* src[20];
  ushort* dst[20];
  int ci[20], co[20], sco[20], sci[20], sk[20];
};

__global__ __launch_bounds__(256)
void prep_all(PrepArgs a, int total) {
  int i = blockIdx.x * 256 + threadIdx.x;
  if (i >= total) return;
  int w = 0;
  while (i >= a.tot[w]) { i -= a.tot[w]; ++w; }
  const int li = i;
  const int CI = a.ci[w];
  int ciX = i % CI;
  int rest = i / CI;
  int coX = rest % a.co[w];
  int k = rest / a.co[w];
  a.dst[w][li] = f2b(a.src[w][coX * a.sco[w] + ciX * a.sci[w] + k * a.sk[w]]);
}

// ======================= fused enc1+enc2 (v2) =======================
__global__ __launch_bounds__(256)
void enc12_mfma(const float* __restrict__ x, const float* __restrict__ w1,
                const float* __restrict__ b1, const ushort* __restrict__ wb,
                const float* __restrict__ b2, ushort* __restrict__ out) {
  constexpr int CI = 64, CO = 128, K = 4, TT = 64;
  constexpr int SPAN = 2 * (TT - 1) + K;       // 130 e1 rows
  __shared__ __align__(16) ushort xs[SPAN * CI];
  __shared__ float xl[264];
  __shared__ float w1s[256];
  __shared__ float b1s[64];

  const int n = blockIdx.x >> 4;
  const int t0 = (blockIdx.x & 15) * TT;
  const int tid = threadIdx.x;
  const int wid = tid >> 6, lane = tid & 63;
  const int l15 = lane & 15, l4 = lane >> 4;

  const int t_in0 = 2 * t0 - 1;
  const int xw0 = 2 * t_in0 - 1;
  const float* xb = x + ((size_t)n << 12);

  for (int j = tid; j < 262; j += 256)
    xl[j] = xb[(xw0 + j + 8192) & 4095];
  if (tid < 256) w1s[tid] = w1[tid];
  if (tid < 64) b1s[tid] = b1[tid];
  __syncthreads();

  const int g = tid & 7;
  float4 wv[8];
  float bs[8];
  #pragma unroll
  for (int e = 0; e < 8; ++e) {
    wv[e] = *reinterpret_cast<const float4*>(&w1s[(g * 8 + e) * 4]);
    bs[e] = b1s[g * 8 + e];
  }
  #pragma unroll
  for (int it = 0; it < 5; ++it) {
    int t = it * 32 + (tid >> 3);
    if (t < SPAN) {
      float x0 = xl[2 * t], x1 = xl[2 * t + 1], x2 = xl[2 * t + 2], x3 = xl[2 * t + 3];
      uint pack[4];
      #pragma unroll
      for (int h = 0; h < 4; ++h) {
        float s0 = fmaf(wv[2 * h].x, x0, fmaf(wv[2 * h].y, x1,
                   fmaf(wv[2 * h].z, x2, fmaf(wv[2 * h].w, x3, bs[2 * h]))));
        float s1 = fmaf(wv[2 * h + 1].x, x0, fmaf(wv[2 * h + 1].y, x1,
                   fmaf(wv[2 * h + 1].z, x2, fmaf(wv[2 * h + 1].w, x3, bs[2 * h + 1]))));
        pack[h] = (uint)f2b(fmaxf(s0, 0.0f)) | ((uint)f2b(fmaxf(s1, 0.0f)) << 16);
      }
      *reinterpret_cast<uint4*>(&xs[t * CI + ((g ^ ((t >> 1) & 7)) * 8)]) =
          uint4{pack[0], pack[1], pack[2], pack[3]};
    }
  }
  __syncthreads();

  const int co_base = wid * 32;
  f32x4 acc[4][2] = {};
  for (int cc = 0; cc < 2; ++cc) {
    bf16x8 bk[K][2];
    #pragma unroll
    for (int k = 0; k < K; ++k)
      #pragma unroll
      for (int c = 0; c < 2; ++c)
        bk[k][c] = __builtin_bit_cast(bf16x8, *reinterpret_cast<const uint4*>(
            wb + (size_t)((k * CO + co_base + c * 16 + l15)) * CI + cc * 32 + l4 * 8));
    #pragma unroll
    for (int k = 0; k < K; ++k) {
      #pragma unroll
      for (int tt2 = 0; tt2 < 4; ++tt2) {
        int trow = 2 * (tt2 * 16 + l15) + k;
        int gg = cc * 4 + l4;
        bf16x8 afr = __builtin_bit_cast(bf16x8, *reinterpret_cast<const uint4*>(
            &xs[trow * CI + ((gg ^ ((trow >> 1) & 7)) * 8)]));
        #pragma unroll
        for (int c = 0; c < 2; ++c)
          acc[tt2][c] = __builtin_amdgcn_mfma_f32_16x16x32_bf16(afr, bk[k][c], acc[tt2][c], 0, 0, 0);
      }
    }
  }
  float bv[2];
  #pragma unroll
  for (int c = 0; c < 2; ++c) bv[c] = b2[co_base + c * 16 + l15];
  ushort* outb = out + (size_t)n * 1024 * CO;
  #pragma unroll
  for (int tt2 = 0; tt2 < 4; ++tt2)
    #pragma unroll
    for (int c = 0; c < 2; ++c)
      #pragma unroll
      for (int r = 0; r < 4; ++r) {
        int t = t0 + tt2 * 16 + 4 * l4 + r;
        int co = co_base + c * 16 + l15;
        outb[(size_t)t * CO + co] = f2b(fmaxf(acc[tt2][c][r] + bv[c], 0.0f));
      }
}

// ======================= generalized MFMA forward conv (optionally ci-chunked) ===============
template<int CI, int CO, int K, int S, bool CIRC, bool GATHER, int NT, int WAVES_CO,
         int NCHUNK = 1>
__global__ __launch_bounds__(256)
void conv_mfma(const ushort* __restrict__ in, const ushort* __restrict__ wb,
               const float* __restrict__ bias, const ushort* __restrict__ resid,
               ushort* __restrict__ out, const int* __restrict__ gidx,
               int Tin, int in_relu, int out_relu) {
  constexpr int PAD = (K > 1) ? 1 : 0;
  constexpr int TT = NT * 16;
  constexpr int SPAN = S * (TT - 1) + K;
  constexpr int CICH = CI / NCHUNK;
  constexpr int CIGc = CICH / 8;
  constexpr int COT = CO / 16;
  constexpr int WCOT = COT / WAVES_CO;
  constexpr int WAVES_T = 4 / WAVES_CO;
  constexpr int WTT = NT / WAVES_T;
  constexpr int KSH = (S == 2) ? 1 : 0;
  static_assert(CICH % 32 == 0 && COT % WAVES_CO == 0 && NT % WAVES_T == 0, "");

  __shared__ __align__(16) ushort xs[SPAN * CICH];

  const int Tout = Tin / S;
  const int tilesPerB = Tout / TT;
  const int n = blockIdx.x / tilesPerB;
  const int t0 = (blockIdx.x % tilesPerB) * TT;
  const int tid = threadIdx.x;
  const int wid = tid >> 6, lane = tid & 63;
  const int l15 = lane & 15, l4 = lane >> 4;

  const int t_in0 = S * t0 - PAD;
  const ushort* inb = GATHER ? in : in + (size_t)n * Tin * CI;

  const int wco = wid % WAVES_CO;
  const int wt = wid / WAVES_CO;
  const int co_base = wco * WCOT * 16;
  const int t_base = wt * WTT * 16;

  f32x4 acc[WTT][WCOT] = {};

  for (int h = 0; h < NCHUNK; ++h) {
    if (h) __syncthreads();
    for (int i = tid; i < SPAN * CIGc; i += 256) {
      int t = i / CIGc, g = i - (i / CIGc) * CIGc;
      int tg = t_in0 + t;
      uint4 v;
      if (CIRC) {
        tg = (tg < 0) ? tg + Tin : (tg >= Tin ? tg - Tin : tg);
        v = *reinterpret_cast<const uint4*>(inb + (size_t)tg * CI + h * CICH + g * 8);
      } else if (GATHER) {
        if ((unsigned)tg < (unsigned)Tin) {
          int id = gidx[n * Tin + tg];
          v = *reinterpret_cast<const uint4*>(inb + (size_t)id * CI + h * CICH + g * 8);
        } else
          v = uint4{0, 0, 0, 0};
      } else {
        if ((unsigned)tg < (unsigned)Tin)
          v = *reinterpret_cast<const uint4*>(inb + (size_t)tg * CI + h * CICH + g * 8);
        else
          v = uint4{0, 0, 0, 0};
      }
      if (in_relu) {
        ushort* pv = reinterpret_cast<ushort*>(&v);
        #pragma unroll
        for (int e = 0; e < 8; ++e) pv[e] = (pv[e] & 0x8000) ? 0 : pv[e];
      }
      *reinterpret_cast<uint4*>(&xs[t * CICH + ((g ^ ((t >> KSH) & (CIGc - 1))) * 8)]) = v;
    }
    __syncthreads();

    for (int cc = 0; cc < CICH / 32; ++cc) {
      const int ccg = h * (CICH / 32) + cc;
      bf16x8 bk[K][WCOT];
      #pragma unroll
      for (int k = 0; k < K; ++k)
        #pragma unroll
        for (int c = 0; c < WCOT; ++c)
          bk[k][c] = __builtin_bit_cast(bf16x8, *reinterpret_cast<const uint4*>(
              wb + (size_t)((k * CO + co_base + c * 16 + l15)) * CI + ccg * 32 + l4 * 8));
      #pragma unroll
      for (int k = 0; k < K; ++k) {
        #pragma unroll
        for (int tt2 = 0; tt2 < WTT; ++tt2) {
          int trow = S * (t_base + tt2 * 16 + l15) + k;
          int g = cc * 4 + l4;
          bf16x8 afr = __builtin_bit_cast(bf16x8, *reinterpret_cast<const uint4*>(
              &xs[trow * CICH + ((g ^ ((trow >> KSH) & (CIGc - 1))) * 8)]));
          #pragma unroll
          for (int c = 0; c < WCOT; ++c)
            acc[tt2][c] = __builtin_amdgcn_mfma_f32_16x16x32_bf16(afr, bk[k][c], acc[tt2][c], 0, 0, 0);
        }
      }
    }
  }

  float bv[WCOT];
  #pragma unroll
  for (int c = 0; c < WCOT; ++c)
    bv[c] = bias ? bias[co_base + c * 16 + l15] : 0.0f;
  ushort* outb = out + (size_t)n * Tout * CO;
  const ushort* resb = resid ? resid + (size_t)n * Tout * CO : nullptr;
  #pragma unroll
  for (int tt2 = 0; tt2 < WTT; ++tt2)
    #pragma unroll
    for (int c = 0; c < WCOT; ++c)
      #pragma unroll
      for (int r = 0; r < 4; ++r) {
        int t = t0 + t_base + tt2 * 16 + 4 * l4 + r;
        int co = co_base + c * 16 + l15;
        float v = acc[tt2][c][r] + bv[c];
        if (resb) v += b2f(resb[(size_t)t * CO + co]);
        if (out_relu) v = fmaxf(v, 0.0f);
        outb[(size_t)t * CO + co] = f2b(v);
      }
}

// ======================= fused residual layer (hs aliased into xs) =======================
__global__ __launch_bounds__(256)
void res_mfma(const ushort* __restrict__ in, const ushort* __restrict__ wb1,
              const ushort* __restrict__ wb2, ushort* __restrict__ out) {
  constexpr int CI = 128, CIG = 16;
  constexpr int TT = 64, SPAN = 66, Tin = 256;
  __shared__ __align__(16) ushort xs[SPAN * CI];
  ushort* hs = xs;
  const int n = blockIdx.x >> 2;
  const int t0 = (blockIdx.x & 3) * TT;
  const int tid = threadIdx.x;
  const int wid = tid >> 6, lane = tid & 63;
  const int l15 = lane & 15, l4 = lane >> 4;
  const int t_in0 = t0 - 1;
  const ushort* inb = in + (size_t)n * Tin * CI;

  for (int i = tid; i < SPAN * CIG; i += 256) {
    int t = i >> 4, g = i & 15;
    int tg = t_in0 + t;
    tg = (tg < 0) ? tg + Tin : (tg >= Tin ? tg - Tin : tg);
    uint4 v = *reinterpret_cast<const uint4*>(inb + (size_t)tg * CI + g * 8);
    ushort* pv = reinterpret_cast<ushort*>(&v);
    #pragma unroll
    for (int e = 0; e < 8; ++e) pv[e] = (pv[e] & 0x8000) ? 0 : pv[e];
    *reinterpret_cast<uint4*>(&xs[t * CI + ((g ^ (t & 15)) * 8)]) = v;
  }
  __syncthreads();

  f32x4 acc1[2] = {};
  for (int cc = 0; cc < 4; ++cc)
    #pragma unroll
    for (int k = 0; k < 3; ++k) {
      bf16x8 bfr[2];
      #pragma unroll
      for (int c = 0; c < 2; ++c)
        bfr[c] = __builtin_bit_cast(bf16x8, *reinterpret_cast<const uint4*>(
            wb1 + (size_t)((k * 32 + c * 16 + l15)) * CI + cc * 32 + l4 * 8));
      int trow = wid * 16 + l15 + k;
      int g = cc * 4 + l4;
      bf16x8 afr = __builtin_bit_cast(bf16x8, *reinterpret_cast<const uint4*>(
          &xs[trow * CI + ((g ^ (trow & 15)) * 8)]));
      acc1[0] = __builtin_amdgcn_mfma_f32_16x16x32_bf16(afr, bfr[0], acc1[0], 0, 0, 0);
      acc1[1] = __builtin_amdgcn_mfma_f32_16x16x32_bf16(afr, bfr[1], acc1[1], 0, 0, 0);
    }
  __syncthreads();
  #pragma unroll
  for (int c = 0; c < 2; ++c)
    #pragma unroll
    for (int r = 0; r < 4; ++r) {
      float v = acc1[c][r];
      hs[(wid * 16 + l4 * 4 + r) * 40 + c * 16 + l15] = (v > 0.0f) ? f2b(v) : (ushort)0;
    }
  __syncthreads();

  {
    bf16x8 afr = *reinterpret_cast<const bf16x8*>(&hs[(wid * 16 + l15) * 40 + l4 * 8]);
    f32x4 acc[8];
    #pragma unroll
    for (int c = 0; c < 8; ++c) {
      bf16x8 bfr = __builtin_bit_cast(bf16x8, *reinterpret_cast<const uint4*>(
          wb2 + (size_t)(c * 16 + l15) * 32 + l4 * 8));
      f32x4 z = {};
      acc[c] = __builtin_amdgcn_mfma_f32_16x16x32_bf16(afr, bfr, z, 0, 0, 0);
    }
    ushort* outb = out + (size_t)n * Tin * CI;
    #pragma unroll
    for (int c = 0; c < 8; ++c)
      #pragma unroll
      for (int r = 0; r < 4; ++r) {
        int t = t0 + wid * 16 + l4 * 4 + r;
        int co = c * 16 + l15;
        float v = acc[c][r] + b2f(inb[(size_t)t * CI + co]);
        outb[(size_t)t * CI + co] = f2b(v);
      }
  }
}

// ======================= MFMA transposed conv k=4 s=2 p=1 (CI=128) =======================
template<int CO>
__global__ __launch_bounds__(256)
void convt_mfma(const ushort* __restrict__ in, const ushort* __restrict__ wb,
                const float* __restrict__ bias, ushort* __restrict__ out,
                int Tin, int in_relu, int out_relu) {
  constexpr int CI = 128, CIG = 16;
  constexpr int NT = 4, TT = 64;
  constexpr int SPAN = TT + 2;
  constexpr int COT = CO / 16;
  constexpr int WCOT = (COT + 3) / 4;
  constexpr int WAVES_CO = COT / WCOT;
  constexpr int WTT = NT;

  __shared__ __align__(16) ushort xs[SPAN * CI];

  const int Tout = 2 * Tin;
  const int tilesPerB = Tin / TT;
  const int n = blockIdx.x / tilesPerB;
  const int tp0 = (blockIdx.x % tilesPerB) * TT;
  const int tid = threadIdx.x;
  const int wid = tid >> 6, lane = tid & 63;
  const int l15 = lane & 15, l4 = lane >> 4;

  const int t_in0 = tp0 - 1;
  const ushort* inb = in + (size_t)n * Tin * CI;
  for (int i = tid; i < SPAN * CIG; i += 256) {
    int t = i >> 4, g = i & 15;
    int tg = t_in0 + t;
    uint4 v;
    if ((unsigned)tg < (unsigned)Tin)
      v = *reinterpret_cast<const uint4*>(inb + (size_t)tg * CI + g * 8);
    else
      v = uint4{0, 0, 0, 0};
    if (in_relu) {
      ushort* pv = reinterpret_cast<ushort*>(&v);
      #pragma unroll
      for (int e = 0; e < 8; ++e) pv[e] = (pv[e] & 0x8000) ? 0 : pv[e];
    }
    *reinterpret_cast<uint4*>(&xs[t * CI + ((g ^ (t & 15)) * 8)]) = v;
  }
  __syncthreads();

  const int wco = wid % WAVES_CO;
  const int co_base = wco * WCOT * 16;

  f32x4 accE[WTT][WCOT] = {};
  f32x4 accO[WTT][WCOT] = {};

  for (int cc = 0; cc < 4; ++cc) {
    bf16x8 bk[4][WCOT];
    #pragma unroll
    for (int k = 0; k < 4; ++k)
      #pragma unroll
      for (int c = 0; c < WCOT; ++c)
        bk[k][c] = __builtin_bit_cast(bf16x8, *reinterpret_cast<const uint4*>(
            wb + (size_t)((k * CO + co_base + c * 16 + l15)) * CI + cc * 32 + l4 * 8));
    #pragma unroll
    for (int tt2 = 0; tt2 < WTT; ++tt2) {
      int lt = tt2 * 16 + l15 + 1;
      int g = cc * 4 + l4;
      bf16x8 a0 = __builtin_bit_cast(bf16x8, *reinterpret_cast<const uint4*>(
          &xs[lt * CI + ((g ^ (lt & 15)) * 8)]));
      bf16x8 am = __builtin_bit_cast(bf16x8, *reinterpret_cast<const uint4*>(
          &xs[(lt - 1) * CI + ((g ^ ((lt - 1) & 15)) * 8)]));
      bf16x8 ap = __builtin_bit_cast(bf16x8, *reinterpret_cast<const uint4*>(
          &xs[(lt + 1) * CI + ((g ^ ((lt + 1) & 15)) * 8)]));
      #pragma unroll
      for (int c = 0; c < WCOT; ++c) {
        accE[tt2][c] = __builtin_amdgcn_mfma_f32_16x16x32_bf16(a0, bk[1][c], accE[tt2][c], 0, 0, 0);
        accE[tt2][c] = __builtin_amdgcn_mfma_f32_16x16x32_bf16(am, bk[3][c], accE[tt2][c], 0, 0, 0);
        accO[tt2][c] = __builtin_amdgcn_mfma_f32_16x16x32_bf16(ap, bk[0][c], accO[tt2][c], 0, 0, 0);
        accO[tt2][c] = __builtin_amdgcn_mfma_f32_16x16x32_bf16(a0, bk[2][c], accO[tt2][c], 0, 0, 0);
      }
    }
  }

  float bv[WCOT];
  #pragma unroll
  for (int c = 0; c < WCOT; ++c) bv[c] = bias[co_base + c * 16 + l15];
  ushort* outb = out + (size_t)n * Tout * CO;
  #pragma unroll
  for (int tt2 = 0; tt2 < WTT; ++tt2)
    #pragma unroll
    for (int c = 0; c < WCOT; ++c)
      #pragma unroll
      for (int r = 0; r < 4; ++r) {
        int tp = tp0 + tt2 * 16 + 4 * l4 + r;
        int co = co_base + c * 16 + l15;
        float vE = accE[tt2][c][r] + bv[c];
        float vO = accO[tt2][c][r] + bv[c];
        if (out_relu) { vE = fmaxf(vE, 0.0f); vO = fmaxf(vO, 0.0f); }
        outb[(size_t)(2 * tp) * CO + co] = f2b(vE);
        outb[(size_t)(2 * tp + 1) * CO + co] = f2b(vO);
      }
}

// ======================= fused ct2+ct3 (TT=64) =======================
// ys transposed [j][66] aliased onto xs; conflict-free; 18.2 KB LDS.
// ct3 phase: 4 independent FMA chains (ILP) instead of one 128-deep chain.
__global__ __launch_bounds__(256)
void ct23_mfma(const ushort* __restrict__ in, const ushort* __restrict__ wb,
               const float* __restrict__ bias, const float* __restrict__ w3,
               const float* __restrict__ b3, float* __restrict__ out) {
  constexpr int CI = 128, CO = 64, CIG = 16;
  constexpr int TT = 64, SPAN = 66, Tin = 1024;
  __shared__ __align__(16) ushort buf[8580];
  __shared__ float2 w3p[2][64];
  ushort* xs = buf;
  ushort* ys = buf;

  const int n = blockIdx.x >> 4;
  const int tp0 = (blockIdx.x & 15) * TT;
  const int tid = threadIdx.x;
  const int wid = tid >> 6, lane = tid & 63;
  const int l15 = lane & 15, l4 = lane >> 4;
  const int t_in0 = tp0 - 1;
  const ushort* inb = in + (size_t)n * Tin * CI;

  if (tid < 128) {
    int parity = tid >> 6, ci = tid & 63;
    w3p[parity][ci] = parity
        ? float2{w3[ci * 4 + 0], w3[ci * 4 + 2]}
        : float2{w3[ci * 4 + 1], w3[ci * 4 + 3]};
  }
  for (int i = tid; i < SPAN * CIG; i += 256) {
    int t = i >> 4, g = i & 15;
    int tg = t_in0 + t;
    uint4 v;
    if ((unsigned)tg < (unsigned)Tin)
      v = *reinterpret_cast<const uint4*>(inb + (size_t)tg * CI + g * 8);
    else
      v = uint4{0, 0, 0, 0};
    *reinterpret_cast<uint4*>(&xs[t * CI + ((g ^ (t & 15)) * 8)]) = v;
  }
  __syncthreads();

  const int co = wid * 16 + l15;
  f32x4 accE[4] = {}, accO[4] = {};
  f32x4 hO = {}, hE = {};

  for (int cc = 0; cc < 4; ++cc) {
    bf16x8 bk[4];
    #pragma unroll
    for (int k = 0; k < 4; ++k)
      bk[k] = __builtin_bit_cast(bf16x8, *reinterpret_cast<const uint4*>(
          wb + (size_t)((k * CO + co)) * CI + cc * 32 + l4 * 8));
    const int g = cc * 4 + l4;
    auto rd = [&](int lt) -> bf16x8 {
      return __builtin_bit_cast(bf16x8, *reinterpret_cast<const uint4*>(
          &xs[lt * CI + ((g ^ (lt & 15)) * 8)]));
    };
    #pragma unroll
    for (int tt2 = 0; tt2 < 4; ++tt2) {
      int lt = tt2 * 16 + l15 + 1;
      bf16x8 a0 = rd(lt), am = rd(lt - 1), ap = rd(lt + 1);
      accE[tt2] = __builtin_amdgcn_mfma_f32_16x16x32_bf16(a0, bk[1], accE[tt2], 0, 0, 0);
      accE[tt2] = __builtin_amdgcn_mfma_f32_16x16x32_bf16(am, bk[3], accE[tt2], 0, 0, 0);
      accO[tt2] = __builtin_amdgcn_mfma_f32_16x16x32_bf16(ap, bk[0], accO[tt2], 0, 0, 0);
      accO[tt2] = __builtin_amdgcn_mfma_f32_16x16x32_bf16(a0, bk[2], accO[tt2], 0, 0, 0);
    }
    bf16x8 h0 = rd(0), h1 = rd(1), h64 = rd(64), h65 = rd(65);
    hO = __builtin_amdgcn_mfma_f32_16x16x32_bf16(h1, bk[0], hO, 0, 0, 0);
    hO = __builtin_amdgcn_mfma_f32_16x16x32_bf16(h0, bk[2], hO, 0, 0, 0);
    hE = __builtin_amdgcn_mfma_f32_16x16x32_bf16(h65, bk[1], hE, 0, 0, 0);
    hE = __builtin_amdgcn_mfma_f32_16x16x32_bf16(h64, bk[3], hE, 0, 0, 0);
  }
  __syncthreads();

  const float bv = bias[co];
  #pragma unroll
  for (int tt2 = 0; tt2 < 4; ++tt2)
    #pragma unroll
    for (int r = 0; r < 4; ++r) {
      int m = tt2 * 16 + 4 * l4 + r;
      ys[(2 * m + 1) * 66 + co] = f2b(fmaxf(accE[tt2][r] + bv, 0.0f));
      ys[(2 * m + 2) * 66 + co] = f2b(fmaxf(accO[tt2][r] + bv, 0.0f));
    }
  if (l4 == 0) {
    ys[co]            = (tp0 == 0) ? (ushort)0 : f2b(fmaxf(hO[0] + bv, 0.0f));
    ys[129 * 66 + co] = (tp0 + TT == Tin) ? (ushort)0 : f2b(fmaxf(hE[0] + bv, 0.0f));
  }
  __syncthreads();

  // ct3: 4 independent accumulator chains (break 128-deep serial FMA chain)
  const int o = 4 * tp0 + tid;
  const int odd = tid & 1;
  const int ha = (tid + odd) >> 1;
  const ushort* ra = &ys[(ha + 1) * 66];
  const ushort* rb = &ys[ha * 66];
  const float2* wp = w3p[odd];
  float s0 = b3[0], s1 = 0.0f, s2 = 0.0f, s3 = 0.0f;
  #pragma unroll
  for (int c = 0; c < 32; ++c) {
    uint va = *reinterpret_cast<const uint*>(ra + 2 * c);
    uint vb = *reinterpret_cast<const uint*>(rb + 2 * c);
    float2 w0 = wp[2 * c], w1 = wp[2 * c + 1];
    s0 = fmaf(w0.x, __uint_as_float(va << 16), s0);
    s1 = fmaf(w1.x, __uint_as_float(va & 0xFFFF0000u), s1);
    s2 = fmaf(w0.y, __uint_as_float(vb << 16), s2);
    s3 = fmaf(w1.y, __uint_as_float(vb & 0xFFFF0000u), s3);
  }
  out[(size_t)n * 4096 + o] = (s0 + s1) + (s2 + s3);
}

// ======================= VQ =======================
__global__ __launch_bounds__(256)
void vq_mfma(const ushort* __restrict__ zt, const ushort* __restrict__ embb,
             int* __restrict__ idx, int* __restrict__ hist,
             float* __restrict__ loss_accum) {
  __shared__ __align__(16) ushort es[512 * 64];
  __shared__ float eel[512];
  __shared__ int lhist[512];
  const int tid = threadIdx.x;
  const int wid = tid >> 6, lane = tid & 63;
  const int l15 = lane & 15, l4 = lane >> 4;

  for (int i = tid; i < 512 * 8; i += 256) {
    int c = i >> 3, g = i & 7;
    uint4 v = reinterpret_cast<const uint4*>(embb)[i];
    reinterpret_cast<uint4*>(es)[c * 8 + (g ^ (c & 7))] = v;
    const ushort* pv = reinterpret_cast<const ushort*>(&v);
    float ss = 0.0f;
    #pragma unroll
    for (int e = 0; e < 8; ++e) { float f = b2f(pv[e]); ss = fmaf(f, f, ss); }
    ss += __shfl_xor(ss, 1);
    ss += __shfl_xor(ss, 2);
    ss += __shfl_xor(ss, 4);
    if ((i & 7) == 0) eel[c] = ss;
  }
  for (int i = tid; i < 512; i += 256) lhist[i] = 0;
  __syncthreads();

  const int rb = blockIdx.x * 256 + wid * 64;
  bf16x8 bz[4][2];
  float zz[4], best[4];
  int bi[4];
  #pragma unroll
  for (int rt = 0; rt < 4; ++rt) {
    const int r = rb + rt * 16 + l15;
    uint4 v0 = *reinterpret_cast<const uint4*>(zt + (size_t)r * 64 + l4 * 8);
    uint4 v1 = *reinterpret_cast<const uint4*>(zt + (size_t)r * 64 + 32 + l4 * 8);
    bz[rt][0] = __builtin_bit_cast(bf16x8, v0);
    bz[rt][1] = __builtin_bit_cast(bf16x8, v1);
    float s = 0.0f;
    const ushort* p0 = reinterpret_cast<const ushort*>(&v0);
    const ushort* p1 = reinterpret_cast<const ushort*>(&v1);
    #pragma unroll
    for (int e = 0; e < 8; ++e) {
      float f0 = b2f(p0[e]), f1 = b2f(p1[e]);
      s = fmaf(f0, f0, fmaf(f1, f1, s));
    }
    s += __shfl_xor(s, 16);
    s += __shfl_xor(s, 32);
    zz[rt] = s;
    best[rt] = 3.4e38f;
    bi[rt] = 0;
  }

  for (int ct = 0; ct < 32; ++ct) {
    const int c = ct * 16 + l15;
    bf16x8 a0 = __builtin_bit_cast(bf16x8, reinterpret_cast<const uint4*>(es)[
        c * 8 + (l4 ^ (c & 7))]);
    bf16x8 a1 = __builtin_bit_cast(bf16x8, reinterpret_cast<const uint4*>(es)[
        c * 8 + ((4 | l4) ^ (c & 7))]);
    #pragma unroll
    for (int rt = 0; rt < 4; ++rt) {
      f32x4 acc = {};
      acc = __builtin_amdgcn_mfma_f32_16x16x32_bf16(a0, bz[rt][0], acc, 0, 0, 0);
      acc = __builtin_amdgcn_mfma_f32_16x16x32_bf16(a1, bz[rt][1], acc, 0, 0, 0);
      #pragma unroll
      for (int rr = 0; rr < 4; ++rr) {
        int code = ct * 16 + l4 * 4 + rr;
        float d = eel[code] - 2.0f * acc[rr];
        if (d < best[rt] || (d == best[rt] && code < bi[rt])) { best[rt] = d; bi[rt] = code; }
      }
    }
  }
  float vsum = 0.0f;
  #pragma unroll
  for (int rt = 0; rt < 4; ++rt) {
    #pragma unroll
    for (int m = 16; m <= 32; m <<= 1) {
      float ob = __shfl_xor(best[rt], m);
      int oi = __shfl_xor(bi[rt], m);
      if (ob < best[rt] || (ob == best[rt] && oi < bi[rt])) { best[rt] = ob; bi[rt] = oi; }
    }
    if (l4 == 0) {
      idx[rb + rt * 16 + l15] = bi[rt];
      atomicAdd(&lhist[bi[rt]], 1);
      vsum += zz[rt] + best[rt];
    }
  }
  #pragma unroll
  for (int m = 1; m < 64; m <<= 1) vsum += __shfl_xor(vsum, m);
  if (lane == 0) atomicAdd(loss_accum, vsum);
  __syncthreads();
  for (int i = tid; i < 512; i += 256)
    if (lhist[i]) atomicAdd(&hist[i], lhist[i]);
}

__global__ __launch_bounds__(512)
void finalize(const int* __restrict__ hist, const float* __restrict__ loss_accum,
              float* __restrict__ out) {
  __shared__ float red[8];
  int tid = threadIdx.x;
  float avg = (float)hist[tid] * (1.0f / 65536.0f);
  float v = avg * logf(avg + 1e-10f);
  for (int off = 32; off > 0; off >>= 1) v += __shfl_down(v, off);
  if ((tid & 63) == 0) red[tid >> 6] = v;
  __syncthreads();
  if (tid == 0) {
    float s = 0.0f;
    for (int i = 0; i < 8; ++i) s += red[i];
    out[1048577] = expf(-s);
    out[0] = 1.25f * loss_accum[0] * (1.0f / (65536.0f * 64.0f));
  }
}

// ======================= launcher =======================
extern "C" void kernel_launch(void* const* d_in, const int* in_sizes, int n_in,
                              void* d_out, int out_size, void* d_ws, size_t ws_size,
                              hipStream_t stream) {
  (void)in_sizes; (void)n_in; (void)out_size; (void)ws_size;
  const float* x    = (const float*)d_in[0];
  const float* c1w  = (const float*)d_in[1];
  const float* c1b  = (const float*)d_in[2];
  const float* c2w  = (const float*)d_in[3];
  const float* c2b  = (const float*)d_in[4];
  const float* c3w  = (const float*)d_in[5];
  const float* c3b  = (const float*)d_in[6];
  const float* c4w  = (const float*)d_in[7];
  const float* c4b  = (const float*)d_in[8];
  const float* cfw  = (const float*)d_in[9];
  const float* cfb  = (const float*)d_in[10];
  const float* erw1 = (const float*)d_in[11];
  const float* erw2 = (const float*)d_in[12];
  const float* pqw  = (const float*)d_in[13];
  const float* pqb  = (const float*)d_in[14];
  const float* emb  = (const float*)d_in[15];
  const float* diw  = (const float*)d_in[16];
  const float* dib  = (const float*)d_in[17];
  const float* drw1 = (const float*)d_in[18];
  const float* drw2 = (const float*)d_in[19];
  const float* t0w  = (const float*)d_in[20];
  const float* t0b  = (const float*)d_in[21];
  const float* t1w  = (const float*)d_in[22];
  const float* t1b  = (const float*)d_in[23];
  const float* t2w  = (const float*)d_in[24];
  const float* t2b  = (const float*)d_in[25];
  const float* t3w  = (const float*)d_in[26];
  const float* t3b  = (const float*)d_in[27];

  char* wsb = (char*)d_ws;
  ushort* R0 = (ushort*)wsb;                           // ct1-out
  ushort* R1 = (ushort*)(wsb + 67108864);              // e2
  ushort* R2 = (ushort*)(wsb + 134217728);             // e3 ; later ct0-out
  ushort* R3 = (ushort*)(wsb + 0);                     // e4 / dec ping
  ushort* R4 = (ushort*)(wsb + 16777216);              // cf / dec pong
  ushort* R6 = (ushort*)(wsb + 37748736);              // zt (BT,64)
  ushort* WPu = (ushort*)(wsb + 167772160);
  ushort* wb_e2 = WPu + 0;
  ushort* wb_e3 = WPu + 32768;
  ushort* wb_e4 = WPu + 98304;
  ushort* wb_cf = WPu + 163840;
  ushort* wb_r1a = WPu + 212992;
  ushort* wb_r1b = WPu + 225280;
  ushort* wb_r2a = WPu + 237568;
  ushort* wb_r2b = WPu + 241664;
  ushort* wb_pq = WPu + 245760;
  ushort* wb_di = WPu + 253952;
  ushort* wb_d1a = WPu + 278528;
  ushort* wb_d1b = WPu + 290816;
  ushort* wb_d2a = WPu + 303104;
  ushort* wb_d2b = WPu + 307200;
  ushort* wb_t0 = WPu + 311296;
  ushort* wb_t1 = WPu + 376832;
  ushort* wb_t2 = WPu + 442368;
  ushort* wb_emb = WPu + 475136;
  char* fp = wsb + 167772160 + 1048576;
  int*   idxb  = (int*)(fp + 2048);
  int*   histb = (int*)(fp + 2048 + 262144);
  float* lossb = (float*)(fp + 2048 + 262144 + 2048);
  float* outp  = (float*)d_out;

  hipMemsetAsync(histb, 0, 512 * sizeof(int), stream);
  hipMemsetAsync(lossb, 0, sizeof(float), stream);

  PrepArgs pa{};
  int nw = 0, total = 0;
  auto addw = [&](const float* src, ushort* dst, int CO, int CI, int K,
                  int sco, int sci, int sk) {
    pa.tot[nw] = K * CO * CI; pa.src[nw] = src; pa.dst[nw] = dst;
    pa.ci[nw] = CI; pa.co[nw] = CO; pa.sco[nw] = sco; pa.sci[nw] = sci; pa.sk[nw] = sk;
    total += pa.tot[nw]; ++nw;
  };
  addw(c2w, wb_e2, 128, 64, 4, 256, 4, 1);
  addw(c3w, wb_e3, 128, 128, 4, 512, 4, 1);
  addw(c4w, wb_e4, 128, 128, 4, 512, 4, 1);
  addw(cfw, wb_cf, 128, 128, 3, 384, 3, 1);
  addw(erw1, wb_r1a, 32, 128, 3, 384, 3, 1);
  addw(erw1 + 12288, wb_r1b, 32, 128, 3, 384, 3, 1);
  addw(erw2, wb_r2a, 128, 32, 1, 32, 1, 1);
  addw(erw2 + 4096, wb_r2b, 128, 32, 1, 32, 1, 1);
  addw(pqw, wb_pq, 64, 128, 1, 128, 1, 1);
  addw(diw, wb_di, 128, 64, 3, 192, 3, 1);
  addw(drw1, wb_d1a, 32, 128, 3, 384, 3, 1);
  addw(drw1 + 12288, wb_d1b, 32, 128, 3, 384, 3, 1);
  addw(drw2, wb_d2a, 128, 32, 1, 32, 1, 1);
  addw(drw2 + 4096, wb_d2b, 128, 32, 1, 32, 1, 1);
  addw(t0w, wb_t0, 128, 128, 4, 4, 512, 1);
  addw(t1w, wb_t1, 128, 128, 4, 4, 512, 1);
  addw(t2w, wb_t2, 64, 128, 4, 4, 256, 1);
  addw(emb, wb_emb, 512, 64, 1, 64, 1, 1);
  pa.nw = nw;
  prep_all<<<(total + 255) / 256, 256, 0, stream>>>(pa, total);

  // ---- encoder ----
  enc12_mfma<<<4096, 256, 0, stream>>>(x, c1w, c1b, wb_e2, c2b, R1);
  conv_mfma<128, 128, 4, 2, true, false, 8, 4, 2><<<1024, 256, 0, stream>>>(R1, wb_e3, c3b, nullptr, R2, nullptr, 1024, 0, 1);
  conv_mfma<128, 128, 4, 2, true, false, 8, 4, 2><<<512, 256, 0, stream>>>(R2, wb_e4, c4b, nullptr, R3, nullptr, 512, 0, 1);
  conv_mfma<128, 128, 3, 1, true, false, 8, 2><<<512, 256, 0, stream>>>(R3, wb_cf, cfb, nullptr, R4, nullptr, 256, 0, 0);
  res_mfma<<<1024, 256, 0, stream>>>(R4, wb_r1a, wb_r2a, R3);
  res_mfma<<<1024, 256, 0, stream>>>(R3, wb_r1b, wb_r2b, R4);
  conv_mfma<128, 64, 1, 1, false, false, 8, 2><<<512, 256, 0, stream>>>(R4, wb_pq, pqb, nullptr, R6, nullptr, 256, 1, 0);
  // ---- VQ ----
  vq_mfma<<<256, 256, 0, stream>>>(R6, wb_emb, idxb, histb, lossb);
  finalize<<<1, 512, 0, stream>>>(histb, lossb, outp);
  // ---- decoder ----
  conv_mfma<64, 128, 3, 1, false, true, 8, 2><<<512, 256, 0, stream>>>(wb_emb, wb_di, dib, nullptr, R3, idxb, 256, 0, 0);
  res_mfma<<<1024, 256, 0, stream>>>(R3, wb_d1a, wb_d2a, R4);
  res_mfma<<<1024, 256, 0, stream>>>(R4, wb_d1b, wb_d2b, R3);
  convt_mfma<128><<<1024, 256, 0, stream>>>(R3, wb_t0, t0b, R2, 256, 1, 1);
  convt_mfma<128><<<2048, 256, 0, stream>>>(R2, wb_t1, t1b, R0, 512, 0, 1);
  ct23_mfma<<<4096, 256, 0, stream>>>(R0, wb_t2, t2b, t3w, t3b, outp + 1);
}